// Round 1
// baseline (2200.220 us; speedup 1.0000x reference)
//
#include <hip/hip_runtime.h>
#include <cstddef>

#define HW96 9216
#define FRAME (64 * 9216)

typedef unsigned short ushort_t;
typedef __attribute__((ext_vector_type(8))) short bf16x8;
typedef __attribute__((ext_vector_type(4))) float f32x4;
typedef __attribute__((ext_vector_type(4))) unsigned u32x4;

// packed u32 = (bf16 hi bits << 16) | bf16 lo bits; value = hi + lo exactly
__device__ __forceinline__ float unpk(unsigned p) {
    return __uint_as_float(p & 0xFFFF0000u) + __uint_as_float(p << 16);
}
__device__ __forceinline__ unsigned pk(float v) {
    unsigned u = __float_as_uint(v);
    unsigned hi = u & 0xFFFF0000u;
    float rem = v - __uint_as_float(hi);
    unsigned r = __float_as_uint(rem);
    unsigned lo = (r + 0x7FFFu + ((r >> 16) & 1u)) >> 16;
    return hi | (lo & 0xFFFFu);
}
__device__ __forceinline__ void split16(float v, ushort_t& h, ushort_t& l) {
    unsigned u = __float_as_uint(v);
    h = (ushort_t)(u >> 16);
    float rem = v - __uint_as_float(u & 0xFFFF0000u);
    unsigned r = __float_as_uint(rem);
    l = (ushort_t)((r + 0x7FFFu + ((r >> 16) & 1u)) >> 16);
}

// ---------------------------------------------------------------------------
// Plain repack: OIHW -> [i][o] fp32 (fusion 1x1 only).
// ---------------------------------------------------------------------------
__global__ __launch_bounds__(256) void repack_fus_k(const float* __restrict__ w,
                                                    float* __restrict__ wp) {
    int idx = blockIdx.x * 256 + threadIdx.x;  // 128*64
    if (idx >= 128 * 64) return;
    int o = idx % 64;
    int i = idx / 64;
    wp[idx] = w[o * 128 + i];
}

// ---------------------------------------------------------------------------
// MFMA A-fragment prepack (16x16x32) with bf16 hi/lo split.
// mode 0 (3x3 conv): layout [hl][t][cc][ot][lane][j]; K = cin chunks of 32.
// mode 1 (dconv):    layout [hl][cc][ot][lane][j]; K = g*72 + tap*8 + c.
// A[m=lane&15][k=(lane>>4)*8+j].
// ---------------------------------------------------------------------------
struct FragJob { const float* src; ushort_t* dst; int O, I, OT, KC, mode; };
struct FragJobs { FragJob j[14]; };

__global__ __launch_bounds__(256) void frag_all_k(FragJobs jobs) {
    const FragJob& J = jobs.j[blockIdx.y];
    int idx = blockIdx.x * 256 + threadIdx.x;
    int total = (J.mode ? 1 : 9) * J.KC * J.OT * 512;
    if (idx >= total) return;
    int jj = idx & 7;
    int lane = (idx >> 3) & 63;
    int rem = idx >> 9;
    int ot = rem % J.OT;
    rem /= J.OT;
    int cc = rem % J.KC;
    int t = rem / J.KC;
    int o = ot * 16 + (lane & 15);
    float wv = 0.f;
    if (J.mode == 0) {
        int ci = cc * 32 + (lane >> 4) * 8 + jj;
        if (o < J.O && ci < J.I) wv = J.src[(o * J.I + ci) * 9 + t];
    } else {
        int K = cc * 32 + (lane >> 4) * 8 + jj;
        int g = K / 72, r2 = K % 72;
        int tap = r2 >> 3, c = r2 & 7;
        int ci = g * 8 + c;
        if (o < J.O && ci < J.I) wv = J.src[(o * J.I + ci) * 9 + tap];
    }
    ushort_t h, l;
    split16(wv, h, l);
    J.dst[idx] = h;
    J.dst[total + idx] = l;
}

// ---------------------------------------------------------------------------
// Transposing pack: planar fp32 frames -> interleaved [px][64ch] packed u32.
// Block handles one 64-px x 64-ch tile via padded LDS. grid (144, T).
// ---------------------------------------------------------------------------
__global__ __launch_bounds__(256) void pack_tr_k(const float* __restrict__ src,
                                                 unsigned* __restrict__ dst) {
    const int t = blockIdx.y;
    const int px0 = blockIdx.x * 64;
    __shared__ unsigned tile[64 * 65];
    const float* s = src + (size_t)t * FRAME;
    unsigned* d = dst + (size_t)t * FRAME;
#pragma unroll
    for (int it = 0; it < 16; ++it) {
        int e = it * 256 + threadIdx.x;
        int p = e & 63, ch = e >> 6;
        tile[ch * 65 + p] = pk(s[(size_t)ch * HW96 + px0 + p]);
    }
    __syncthreads();
#pragma unroll
    for (int it = 0; it < 16; ++it) {
        int e = it * 256 + threadIdx.x;
        int ch = e & 63, p = e >> 6;
        d[(size_t)(px0 + p) * 64 + ch] = tile[ch * 65 + p];
    }
}

// ---------------------------------------------------------------------------
// MFMA implicit-GEMM 3x3 conv, 16x16x32 bf16, 3-term hi/lo split.
// NOW 512 threads = 8 waves: wave pairs split the two 32-ch halves (cc2) of
// each source; waves 4-7 dump partials to LDS, waves 0-3 reduce + epilogue.
// Block tile = 64 out x 16 px; sources INTERLEAVED [px][64ch] packed u32.
// ---------------------------------------------------------------------------
__global__ __launch_bounds__(512) void convm_k(
    const unsigned* __restrict__ s0, const unsigned* __restrict__ s1,
    const unsigned* __restrict__ s2, int b0, int b1, int b2, int nsrc,
    const ushort_t* __restrict__ wfrag, int KCfull,
    const float* __restrict__ bias, const float* __restrict__ addsrc,
    unsigned* __restrict__ outpk, int act) {
    const int tid = threadIdx.x;
    const int lane = tid & 63;
    const int w = tid >> 6;      // 0..7
    const int ot = w & 3;        // out-tile (16 couts)
    const int pg = w >> 2;       // cc2 half owned by this wave
    const int xb = (blockIdx.x % 6) * 16;
    const int y = blockIdx.x / 6;
    const int n = lane & 15;
    const int quad = lane >> 4;

    __shared__ __align__(16) ushort_t ldsH[3 * 18 * 72];
    __shared__ __align__(16) ushort_t ldsL[3 * 18 * 72];
    __shared__ __align__(16) float part[4 * 64 * 4];

    // staging job decode (loop-invariant): 432 jobs, 1 per thread (tid<432)
    const int jst = (tid < 432);
    const int rc = tid >> 3, cg = tid & 7;
    const int r0 = rc / 18, col0 = rc - r0 * 18;
    const int gy = y - 1 + r0, gx = xb - 1 + col0;
    const int jok = jst && ((unsigned)gy < 96u) && ((unsigned)gx < 96u);
    const int joff = (gy * 96 + gx) * 64 + cg * 8;
    const int jbase = rc * 72 + cg * 8;

    f32x4 acc0, acc1;
#pragma unroll
    for (int r = 0; r < 4; ++r) { acc0[r] = 0.f; acc1[r] = 0.f; }

    const size_t hlOff = (size_t)9 * KCfull * 4 * 512;

    for (int j = 0; j < nsrc; ++j) {
        const unsigned* sv = (j == 0) ? s0 : (j == 1 ? s1 : s2);
        const int base = (j == 0) ? b0 : (j == 1 ? b1 : b2);
        __syncthreads();
        if (jst) {
            u32x4 a, b;
            if (jok) {
                a = *(const u32x4*)(sv + joff);
                b = *(const u32x4*)(sv + joff + 4);
            } else {
#pragma unroll
                for (int q = 0; q < 4; ++q) { a[q] = 0; b[q] = 0; }
            }
            u32x4 H, L;
#pragma unroll
            for (int q = 0; q < 2; ++q) {
                H[q] = (a[2 * q] >> 16) | (a[2 * q + 1] & 0xFFFF0000u);
                L[q] = (a[2 * q] & 0xFFFFu) | (a[2 * q + 1] << 16);
                H[2 + q] = (b[2 * q] >> 16) | (b[2 * q + 1] & 0xFFFF0000u);
                L[2 + q] = (b[2 * q] & 0xFFFFu) | (b[2 * q + 1] << 16);
            }
            *(u32x4*)(ldsH + jbase) = H;
            *(u32x4*)(ldsL + jbase) = L;
        }
        __syncthreads();
        const int ccor = base + pg;
#pragma unroll
        for (int t = 0; t < 9; ++t) {
            const int ky = t / 3, kx = t % 3;
            const ushort_t* ab =
                wfrag + (((size_t)(t * KCfull + ccor) * 4 + ot) * 64 + lane) * 8;
            bf16x8 Ah = *(const bf16x8*)ab;
            bf16x8 Al = *(const bf16x8*)(ab + hlOff);
            int lb = (ky * 18 + n + kx) * 72 + pg * 32 + quad * 8;
            bf16x8 Bh = *(const bf16x8*)(ldsH + lb);
            bf16x8 Bl = *(const bf16x8*)(ldsL + lb);
            if (t & 1) {
                acc1 = __builtin_amdgcn_mfma_f32_16x16x32_bf16(Ah, Bh, acc1, 0, 0, 0);
                acc1 = __builtin_amdgcn_mfma_f32_16x16x32_bf16(Al, Bh, acc1, 0, 0, 0);
                acc1 = __builtin_amdgcn_mfma_f32_16x16x32_bf16(Ah, Bl, acc1, 0, 0, 0);
            } else {
                acc0 = __builtin_amdgcn_mfma_f32_16x16x32_bf16(Ah, Bh, acc0, 0, 0, 0);
                acc0 = __builtin_amdgcn_mfma_f32_16x16x32_bf16(Al, Bh, acc0, 0, 0, 0);
                acc0 = __builtin_amdgcn_mfma_f32_16x16x32_bf16(Ah, Bl, acc0, 0, 0, 0);
            }
        }
    }

    if (pg == 1) {
        f32x4 s;
#pragma unroll
        for (int r = 0; r < 4; ++r) s[r] = acc0[r] + acc1[r];
        *(f32x4*)(part + (ot * 64 + lane) * 4) = s;
    }
    __syncthreads();
    if (pg == 0) {
        const int px = y * 96 + xb + n;
        const f32x4 pp = *(const f32x4*)(part + (ot * 64 + lane) * 4);
#pragma unroll
        for (int r = 0; r < 4; ++r) {
            int cout = ot * 16 + quad * 4 + r;
            float v = acc0[r] + acc1[r] + pp[r] + bias[cout];
            if (act) v = (v >= 0.f) ? v : 0.1f * v;
            if (addsrc) v += addsrc[(size_t)cout * HW96 + px];
            outpk[(size_t)px * 64 + cout] = pk(v);
        }
    }
}

// ---------------------------------------------------------------------------
// Fused ow4 (64->432 conv) + modulated deformable conv v2.
// NOW 512 threads = 8 waves: phase 2 splits 28 out-tiles over 8 waves;
// phase 3 splits the cc (K) space by parity over wave pairs, with an LDS
// partial reduce through the (then-dead) rawS region.
// ---------------------------------------------------------------------------
__global__ __launch_bounds__(512) void dconv_fused_k(
    const unsigned* __restrict__ sA, const unsigned* __restrict__ sB,
    const unsigned* __restrict__ hA, const ushort_t* __restrict__ w4,
    const float* __restrict__ ob4, const ushort_t* __restrict__ dwf,
    const float* __restrict__ dbias, int ngr4, float* __restrict__ outf,
    unsigned* __restrict__ outpk) {
    const int tid = threadIdx.x;
    const int lane = tid & 63;
    const int w = tid >> 6;  // 0..7
    const int xb = (blockIdx.x % 6) * 16;
    const int y = blockIdx.x / 6;
    const int n = lane & 15;
    const int quad = lane >> 4;

    __shared__ __align__(16) char smem[18944 + 448 * 17 * 4];
    ushort_t* ldsAH = (ushort_t*)smem;        // 3888 ushorts
    ushort_t* ldsAL = ldsAH + 3888;
    ushort_t* colsH = (ushort_t*)smem;        // 16*296 ushorts (union)
    ushort_t* colsL = colsH + 4736;
    float* rawS = (float*)(smem + 18944);     // [448][17] fp32

    // ---- phase 1: stage hA window (interleaved source), 1 job/thread ----
    if (tid < 432) {
        int rc = tid >> 3, cg = tid & 7;
        int r = rc / 18, col = rc - r * 18;
        int gy = y - 1 + r, gx = xb - 1 + col;
        bool ok = ((unsigned)gy < 96u) && ((unsigned)gx < 96u);
        u32x4 a, b;
        if (ok) {
            int off = (gy * 96 + gx) * 64 + cg * 8;
            a = *(const u32x4*)(hA + off);
            b = *(const u32x4*)(hA + off + 4);
        } else {
#pragma unroll
            for (int q = 0; q < 4; ++q) { a[q] = 0; b[q] = 0; }
        }
        u32x4 H, L;
#pragma unroll
        for (int q = 0; q < 2; ++q) {
            H[q] = (a[2 * q] >> 16) | (a[2 * q + 1] & 0xFFFF0000u);
            L[q] = (a[2 * q] & 0xFFFFu) | (a[2 * q + 1] << 16);
            H[2 + q] = (b[2 * q] >> 16) | (b[2 * q + 1] & 0xFFFF0000u);
            L[2 + q] = (b[2 * q] & 0xFFFFu) | (b[2 * q + 1] << 16);
        }
        *(u32x4*)(ldsAH + rc * 72 + cg * 8) = H;
        *(u32x4*)(ldsAL + rc * 72 + cg * 8) = L;
    }
    __syncthreads();

    // ---- phase 2: raw = ow4(hA), 28 out-tiles over 8 waves ----
    const size_t hl4 = (size_t)9 * 2 * 28 * 512;
#pragma unroll 1
    for (int j = 0; j < 4; ++j) {
        const int ot = j * 8 + w;
        if (ot >= 28) break;
        f32x4 a0, a1;
#pragma unroll
        for (int r = 0; r < 4; ++r) { a0[r] = 0.f; a1[r] = 0.f; }
#pragma unroll
        for (int t = 0; t < 9; ++t) {
            const int ky = t / 3, kx = t % 3;
#pragma unroll
            for (int cc2 = 0; cc2 < 2; ++cc2) {
                const ushort_t* ab =
                    w4 + (((size_t)(t * 2 + cc2) * 28 + ot) * 64 + lane) * 8;
                bf16x8 Ah = *(const bf16x8*)ab;
                bf16x8 Al = *(const bf16x8*)(ab + hl4);
                int lb = (ky * 18 + n + kx) * 72 + cc2 * 32 + quad * 8;
                bf16x8 Bh = *(const bf16x8*)(ldsAH + lb);
                bf16x8 Bl = *(const bf16x8*)(ldsAL + lb);
                if ((t * 2 + cc2) & 1) {
                    a1 = __builtin_amdgcn_mfma_f32_16x16x32_bf16(Ah, Bh, a1, 0, 0, 0);
                    a1 = __builtin_amdgcn_mfma_f32_16x16x32_bf16(Al, Bh, a1, 0, 0, 0);
                    a1 = __builtin_amdgcn_mfma_f32_16x16x32_bf16(Ah, Bl, a1, 0, 0, 0);
                } else {
                    a0 = __builtin_amdgcn_mfma_f32_16x16x32_bf16(Ah, Bh, a0, 0, 0, 0);
                    a0 = __builtin_amdgcn_mfma_f32_16x16x32_bf16(Al, Bh, a0, 0, 0, 0);
                    a0 = __builtin_amdgcn_mfma_f32_16x16x32_bf16(Ah, Bl, a0, 0, 0, 0);
                }
            }
        }
#pragma unroll
        for (int r = 0; r < 4; ++r) {
            int cout = ot * 16 + quad * 4 + r;
            float v = a0[r] + a1[r] + (cout < 432 ? ob4[cout] : 0.f);
            rawS[cout * 17 + n] = v;
        }
    }

    // ---- phase 3: gather + dconv MFMA (cc parity split over wave pairs) ----
    const int otD = w & 3;
    const int pg = w >> 2;
    f32x4 acc0, acc1;
#pragma unroll
    for (int r = 0; r < 4; ++r) { acc0[r] = 0.f; acc1[r] = 0.f; }
    const size_t hlD = (size_t)36 * 4 * 512;

    for (int gc = 0; gc < ngr4; ++gc) {
        __syncthreads();  // rawS ready / cols reuse safe
#pragma unroll
        for (int i = 0; i < 2; ++i) {
            int e = tid + i * 512;
            if (e < 576) {
                int p = e & 15;
                int r = e >> 4;  // 0..35
                int gl = r / 9, k = r - gl * 9;
                int g = gc * 4 + gl;
                float ry = rawS[(g * 18 + k * 2 + 0) * 17 + p];
                float rx = rawS[(g * 18 + k * 2 + 1) * 17 + p];
                float rm = rawS[(288 + g * 9 + k) * 17 + p];
                float oy = 5.f * (1.f - 2.f / (1.f + __expf(2.f * ry)));
                float ox = 5.f * (1.f - 2.f / (1.f + __expf(2.f * rx)));
                float m = 1.f / (1.f + __expf(-rm));
                float sy = oy + (float)(y - 1 + k / 3);
                float sx = ox + (float)(xb + p - 1 + k % 3);
                float fy0 = floorf(sy), fx0 = floorf(sx);
                float fy = sy - fy0, fx = sx - fx0;
                int y0 = (int)fy0, x0 = (int)fx0;
                int y1 = y0 + 1, x1 = x0 + 1;
                bool vy0 = (unsigned)y0 < 96u, vy1 = (unsigned)y1 < 96u;
                bool vx0 = (unsigned)x0 < 96u, vx1 = (unsigned)x1 < 96u;
                int cy0 = min(max(y0, 0), 95), cy1 = min(max(y1, 0), 95);
                int cx0 = min(max(x0, 0), 95), cx1 = min(max(x1, 0), 95);
                float w00 = (1.f - fy) * (1.f - fx) * ((vy0 && vx0) ? 1.f : 0.f);
                float w01 = (1.f - fy) * fx * ((vy0 && vx1) ? 1.f : 0.f);
                float w10 = fy * (1.f - fx) * ((vy1 && vx0) ? 1.f : 0.f);
                float w11 = fy * fx * ((vy1 && vx1) ? 1.f : 0.f);
                const unsigned* src = (g < 8) ? sA : sB;
                int cb = (g & 7) * 8;
                int kbase = p * 296 + gl * 72 + k * 8;
                ushort_t hh[8], ll[8];
                if (src) {
                    int b00 = (cy0 * 96 + cx0) * 64 + cb;
                    int b01 = (cy0 * 96 + cx1) * 64 + cb;
                    int b10 = (cy1 * 96 + cx0) * 64 + cb;
                    int b11 = (cy1 * 96 + cx1) * 64 + cb;
                    u32x4 c00a = *(const u32x4*)(src + b00);
                    u32x4 c00b = *(const u32x4*)(src + b00 + 4);
                    u32x4 c01a = *(const u32x4*)(src + b01);
                    u32x4 c01b = *(const u32x4*)(src + b01 + 4);
                    u32x4 c10a = *(const u32x4*)(src + b10);
                    u32x4 c10b = *(const u32x4*)(src + b10 + 4);
                    u32x4 c11a = *(const u32x4*)(src + b11);
                    u32x4 c11b = *(const u32x4*)(src + b11 + 4);
#pragma unroll
                    for (int c = 0; c < 4; ++c) {
                        float v = w00 * unpk(c00a[c]) + w01 * unpk(c01a[c]) +
                                  w10 * unpk(c10a[c]) + w11 * unpk(c11a[c]);
                        split16(v * m, hh[c], ll[c]);
                        float v2 = w00 * unpk(c00b[c]) + w01 * unpk(c01b[c]) +
                                   w10 * unpk(c10b[c]) + w11 * unpk(c11b[c]);
                        split16(v2 * m, hh[4 + c], ll[4 + c]);
                    }
                } else {
#pragma unroll
                    for (int c = 0; c < 8; ++c) { hh[c] = 0; ll[c] = 0; }
                }
                u32x4 H, L;
#pragma unroll
                for (int q = 0; q < 4; ++q) {
                    H[q] = (unsigned)hh[2 * q] | ((unsigned)hh[2 * q + 1] << 16);
                    L[q] = (unsigned)ll[2 * q] | ((unsigned)ll[2 * q + 1] << 16);
                }
                *(u32x4*)(colsH + kbase) = H;
                *(u32x4*)(colsL + kbase) = L;
            }
        }
        __syncthreads();
#pragma unroll
        for (int cc2 = 0; cc2 < 9; ++cc2) {
            int cc = gc * 9 + cc2;
            if ((cc & 1) != pg) continue;
            const ushort_t* ab = dwf + (((size_t)cc * 4 + otD) * 64 + lane) * 8;
            bf16x8 Ah = *(const bf16x8*)ab;
            bf16x8 Al = *(const bf16x8*)(ab + hlD);
            int lb = n * 296 + cc2 * 32 + quad * 8;
            bf16x8 Bh = *(const bf16x8*)(colsH + lb);
            bf16x8 Bl = *(const bf16x8*)(colsL + lb);
            if ((cc >> 1) & 1) {
                acc1 = __builtin_amdgcn_mfma_f32_16x16x32_bf16(Ah, Bh, acc1, 0, 0, 0);
                acc1 = __builtin_amdgcn_mfma_f32_16x16x32_bf16(Al, Bh, acc1, 0, 0, 0);
                acc1 = __builtin_amdgcn_mfma_f32_16x16x32_bf16(Ah, Bl, acc1, 0, 0, 0);
            } else {
                acc0 = __builtin_amdgcn_mfma_f32_16x16x32_bf16(Ah, Bh, acc0, 0, 0, 0);
                acc0 = __builtin_amdgcn_mfma_f32_16x16x32_bf16(Al, Bh, acc0, 0, 0, 0);
                acc0 = __builtin_amdgcn_mfma_f32_16x16x32_bf16(Ah, Bl, acc0, 0, 0, 0);
            }
        }
    }

    // partial reduce: waves 4-7 dump into (now-dead) rawS region
    if (pg == 1) {
        f32x4 s;
#pragma unroll
        for (int r = 0; r < 4; ++r) s[r] = acc0[r] + acc1[r];
        *(f32x4*)(rawS + (otD * 64 + lane) * 4) = s;
    }
    __syncthreads();
    if (pg == 0) {
        const int pidx = y * 96 + xb + n;
        const f32x4 pp = *(const f32x4*)(rawS + (otD * 64 + lane) * 4);
#pragma unroll
        for (int r = 0; r < 4; ++r) {
            int cout = otD * 16 + quad * 4 + r;
            float v = acc0[r] + acc1[r] + pp[r] + dbias[cout];
            outf[(size_t)cout * HW96 + pidx] = v;
            outpk[(size_t)pidx * 64 + cout] = pk(v);
        }
    }
}

// ---------------------------------------------------------------------------
// Fusion: 1x1 conv over [featB[t], featF[t]] (interleaved) + bias + x.
// ---------------------------------------------------------------------------
__global__ __launch_bounds__(256) void fuse_k(
    const unsigned* __restrict__ featB, const unsigned* __restrict__ featF,
    const float* __restrict__ x, const float* __restrict__ wp,
    const float* __restrict__ bias, float* __restrict__ out) {
    const int tx = threadIdx.x & 31;
    const int ty = threadIdx.x >> 5;
    const int px = blockIdx.x * 32 + tx;
    const int py = blockIdx.y * 8 + ty;
    const int t = blockIdx.z >> 3;
    const int obase = (blockIdx.z & 7) * 8;
    const int pidx = py * 96 + px;
    const unsigned* fB = featB + (size_t)t * FRAME + (size_t)pidx * 64;
    const unsigned* fF = featF + (size_t)t * FRAME + (size_t)pidx * 64;

    float acc[8];
#pragma unroll
    for (int o = 0; o < 8; ++o) acc[o] = 0.f;

#pragma unroll 4
    for (int i0 = 0; i0 < 64; i0 += 4) {
        u32x4 pv = *(const u32x4*)(fB + i0);
#pragma unroll
        for (int q = 0; q < 4; ++q) {
            float v = unpk(pv[q]);
            const float* wr = wp + (i0 + q) * 64 + obase;
#pragma unroll
            for (int o = 0; o < 8; ++o) acc[o] = fmaf(wr[o], v, acc[o]);
        }
    }
#pragma unroll 4
    for (int i0 = 0; i0 < 64; i0 += 4) {
        u32x4 pv = *(const u32x4*)(fF + i0);
#pragma unroll
        for (int q = 0; q < 4; ++q) {
            float v = unpk(pv[q]);
            const float* wr = wp + (64 + i0 + q) * 64 + obase;
#pragma unroll
            for (int o = 0; o < 8; ++o) acc[o] = fmaf(wr[o], v, acc[o]);
        }
    }
    const float* xt = x + (size_t)t * FRAME;
#pragma unroll
    for (int o = 0; o < 8; ++o)
        out[(size_t)t * FRAME + (size_t)(obase + o) * HW96 + pidx] =
            acc[o] + bias[obase + o] + xt[(size_t)(obase + o) * HW96 + pidx];
}

// ---------------------------------------------------------------------------
extern "C" void kernel_launch(void* const* d_in, const int* in_sizes, int n_in,
                              void* d_out, int out_size, void* d_ws,
                              size_t ws_size, hipStream_t stream) {
    const float* x = (const float*)d_in[0];
    auto gp = [&](int i) { return (const float*)d_in[i]; };

    struct DirP {
        const float *dw, *db, *ow1, *ob1, *ow2, *ob2, *ow3, *ob3, *ow4, *ob4,
            *bw1, *bb1, *bw2, *bb2;
    };
    DirP Pb{gp(1), gp(2), gp(3), gp(4), gp(5), gp(6), gp(7),
            gp(8), gp(9), gp(10), gp(11), gp(12), gp(13), gp(14)};
    DirP Pf{gp(15), gp(16), gp(17), gp(18), gp(19), gp(20), gp(21),
            gp(22), gp(23), gp(24), gp(25), gp(26), gp(27), gp(28)};
    const float* fus_w = gp(29);
    const float* fus_b = gp(30);

    // ---- workspace carve-up (4-byte units); all feature bufs interleaved ----
    unsigned* featBpk = (unsigned*)d_ws;
    unsigned* featFpk = featBpk + (size_t)8 * FRAME;
    unsigned* xpk = featFpk + (size_t)8 * FRAME;
    float* Dbuf = (float*)(xpk + (size_t)8 * FRAME);  // planar fp32
    unsigned* Dpk = (unsigned*)(Dbuf + FRAME);        // interleaved packed
    unsigned* hApk = Dpk + FRAME;
    unsigned* hBpk = hApk + FRAME;
    float* wfus = (float*)(hBpk + FRAME);
    ushort_t* fragp = (ushort_t*)(wfus + 128 * 64);

    auto falloc = [&](size_t nelem) {
        ushort_t* p = fragp;
        fragp += nelem;
        return p;
    };

    // ---- weight prep ----
    repack_fus_k<<<32, 256, 0, stream>>>(fus_w, wfus);

    struct DirW { ushort_t *ow1, *ow2, *ow3, *ow4, *bw1, *bw2, *dw; int bw1KC; };
    FragJobs fj;
    int nf = 0;
    auto fjob = [&](const float* src, int O, int I, int OT, int KC) {
        ushort_t* dst = falloc((size_t)2 * 9 * KC * OT * 512);
        fj.j[nf++] = FragJob{src, dst, O, I, OT, KC, 0};
        return dst;
    };
    auto fjobd = [&](const float* src) {
        ushort_t* dst = falloc((size_t)2 * 36 * 4 * 512);
        fj.j[nf++] = FragJob{src, dst, 64, 128, 4, 36, 1};
        return dst;
    };
    DirW Wb, Wf;
    Wb.ow1 = fjob(Pb.ow1, 64, 192, 4, 6);
    Wb.ow2 = fjob(Pb.ow2, 64, 64, 4, 2);
    Wb.ow3 = fjob(Pb.ow3, 64, 64, 4, 2);
    Wb.ow4 = fjob(Pb.ow4, 432, 64, 28, 2);
    Wb.bw1 = fjob(Pb.bw1, 64, 128, 4, 4);
    Wb.bw1KC = 4;
    Wb.bw2 = fjob(Pb.bw2, 64, 64, 4, 2);
    Wb.dw = fjobd(Pb.dw);
    Wf.ow1 = fjob(Pf.ow1, 64, 192, 4, 6);
    Wf.ow2 = fjob(Pf.ow2, 64, 64, 4, 2);
    Wf.ow3 = fjob(Pf.ow3, 64, 64, 4, 2);
    Wf.ow4 = fjob(Pf.ow4, 432, 64, 28, 2);
    Wf.bw1 = fjob(Pf.bw1, 64, 192, 4, 6);
    Wf.bw1KC = 6;
    Wf.bw2 = fjob(Pf.bw2, 64, 64, 4, 2);
    Wf.dw = fjobd(Pf.dw);
    frag_all_k<<<dim3(1008, 14), 256, 0, stream>>>(fj);

    pack_tr_k<<<dim3(144, 8), 256, 0, stream>>>(x, xpk);

    auto convm = [&](const unsigned* a, const unsigned* b, const unsigned* c2,
                     const ushort_t* frag, int KCfull, const float* bias,
                     const float* addsrc, unsigned* out, int act) {
        const unsigned* srcs[3] = {a, b, c2};
        const unsigned* S[3] = {nullptr, nullptr, nullptr};
        int B[3] = {0, 0, 0};
        int ns = 0;
        for (int j = 0; j < 3; ++j)
            if (srcs[j]) {
                S[ns] = srcs[j];
                B[ns] = j * 2;
                ++ns;
            }
        convm_k<<<576, 512, 0, stream>>>(S[0], S[1], S[2], B[0], B[1], B[2],
                                         ns, frag, KCfull, bias, addsrc, out,
                                         act);
    };

    for (int dir = 0; dir < 2; ++dir) {  // 0 = backward, 1 = forward
        const DirP& P = dir ? Pf : Pb;
        const DirW& W = dir ? Wf : Wb;
        unsigned* feat = dir ? featFpk : featBpk;
        const unsigned* prev1 = nullptr;
        const unsigned* prev2 = nullptr;
        for (int i = 0; i < 8; ++i) {
            int idx = dir ? i : 7 - i;
            const unsigned* cur = xpk + (size_t)idx * FRAME;
            const float* propf = nullptr;
            if (i > 0) {
                convm(prev1, cur, prev2, W.ow1, 6, P.ob1, nullptr, hApk, 1);
                convm(hApk, nullptr, nullptr, W.ow2, 2, P.ob2, nullptr, hBpk, 1);
                convm(hBpk, nullptr, nullptr, W.ow3, 2, P.ob3, nullptr, hApk, 1);
                int ngr4 = (prev2 != nullptr) ? 4 : 2;
                dconv_fused_k<<<576, 512, 0, stream>>>(
                    prev1, prev2, hApk, W.ow4, P.ob4, W.dw, P.db, ngr4, Dbuf,
                    Dpk);
                propf = Dbuf;
            }
            unsigned* dst = feat + (size_t)idx * FRAME;
            if (dir == 0) {
                convm(cur, (i > 0) ? Dpk : nullptr, nullptr, W.bw1, W.bw1KC,
                      P.bb1, nullptr, hBpk, 1);
            } else {
                convm(cur, featBpk + (size_t)idx * FRAME,
                      (i > 0) ? Dpk : nullptr, W.bw1, W.bw1KC, P.bb1, nullptr,
                      hBpk, 1);
            }
            convm(hBpk, nullptr, nullptr, W.bw2, 2, P.bb2, propf, dst, 0);
            prev2 = prev1;
            prev1 = dst;
        }
    }

    fuse_k<<<dim3(3, 12, 64), 256, 0, stream>>>(featBpk, featFpk, x, wfus,
                                                fus_b, (float*)d_out);
}

// Round 2
// 1888.984 us; speedup vs baseline: 1.1648x; 1.1648x over previous
//
#include <hip/hip_runtime.h>
#include <cstddef>

#define HW96 9216
#define FRAME (64 * 9216)

typedef unsigned short ushort_t;
typedef __attribute__((ext_vector_type(8))) short bf16x8;
typedef __attribute__((ext_vector_type(4))) float f32x4;
typedef __attribute__((ext_vector_type(4))) unsigned u32x4;

// packed u32 = (bf16 hi bits << 16) | bf16 lo bits; value = hi + lo exactly
__device__ __forceinline__ float unpk(unsigned p) {
    return __uint_as_float(p & 0xFFFF0000u) + __uint_as_float(p << 16);
}
__device__ __forceinline__ unsigned pk(float v) {
    unsigned u = __float_as_uint(v);
    unsigned hi = u & 0xFFFF0000u;
    float rem = v - __uint_as_float(hi);
    unsigned r = __float_as_uint(rem);
    unsigned lo = (r + 0x7FFFu + ((r >> 16) & 1u)) >> 16;
    return hi | (lo & 0xFFFFu);
}
__device__ __forceinline__ void split16(float v, ushort_t& h, ushort_t& l) {
    unsigned u = __float_as_uint(v);
    h = (ushort_t)(u >> 16);
    float rem = v - __uint_as_float(u & 0xFFFF0000u);
    unsigned r = __float_as_uint(rem);
    l = (ushort_t)((r + 0x7FFFu + ((r >> 16) & 1u)) >> 16);
}

// ---------------------------------------------------------------------------
// Plain repack: OIHW -> [i][o] fp32 (fusion 1x1 only).
// ---------------------------------------------------------------------------
__global__ __launch_bounds__(256) void repack_fus_k(const float* __restrict__ w,
                                                    float* __restrict__ wp) {
    int idx = blockIdx.x * 256 + threadIdx.x;  // 128*64
    if (idx >= 128 * 64) return;
    int o = idx % 64;
    int i = idx / 64;
    wp[idx] = w[o * 128 + i];
}

// ---------------------------------------------------------------------------
// MFMA A-fragment prepack (16x16x32) with bf16 hi/lo split.
// mode 0 (3x3 conv): layout [hl][t][cc][ot][lane][j]; K = cin chunks of 32.
// mode 1 (dconv):    layout [hl][cc][ot][lane][j]; K = g*72 + tap*8 + c.
// A[m=lane&15][k=(lane>>4)*8+j].
// ---------------------------------------------------------------------------
struct FragJob { const float* src; ushort_t* dst; int O, I, OT, KC, mode; };
struct FragJobs { FragJob j[14]; };

__global__ __launch_bounds__(256) void frag_all_k(FragJobs jobs) {
    const FragJob& J = jobs.j[blockIdx.y];
    int idx = blockIdx.x * 256 + threadIdx.x;
    int total = (J.mode ? 1 : 9) * J.KC * J.OT * 512;
    if (idx >= total) return;
    int jj = idx & 7;
    int lane = (idx >> 3) & 63;
    int rem = idx >> 9;
    int ot = rem % J.OT;
    rem /= J.OT;
    int cc = rem % J.KC;
    int t = rem / J.KC;
    int o = ot * 16 + (lane & 15);
    float wv = 0.f;
    if (J.mode == 0) {
        int ci = cc * 32 + (lane >> 4) * 8 + jj;
        if (o < J.O && ci < J.I) wv = J.src[(o * J.I + ci) * 9 + t];
    } else {
        int K = cc * 32 + (lane >> 4) * 8 + jj;
        int g = K / 72, r2 = K % 72;
        int tap = r2 >> 3, c = r2 & 7;
        int ci = g * 8 + c;
        if (o < J.O && ci < J.I) wv = J.src[(o * J.I + ci) * 9 + tap];
    }
    ushort_t h, l;
    split16(wv, h, l);
    J.dst[idx] = h;
    J.dst[total + idx] = l;
}

// ---------------------------------------------------------------------------
// Transposing pack: planar fp32 frames -> interleaved [px][64ch] packed u32.
// Block handles one 64-px x 64-ch tile via padded LDS. grid (144, T).
// ---------------------------------------------------------------------------
__global__ __launch_bounds__(256) void pack_tr_k(const float* __restrict__ src,
                                                 unsigned* __restrict__ dst) {
    const int t = blockIdx.y;
    const int px0 = blockIdx.x * 64;
    __shared__ unsigned tile[64 * 65];
    const float* s = src + (size_t)t * FRAME;
    unsigned* d = dst + (size_t)t * FRAME;
#pragma unroll
    for (int it = 0; it < 16; ++it) {
        int e = it * 256 + threadIdx.x;
        int p = e & 63, ch = e >> 6;
        tile[ch * 65 + p] = pk(s[(size_t)ch * HW96 + px0 + p]);
    }
    __syncthreads();
#pragma unroll
    for (int it = 0; it < 16; ++it) {
        int e = it * 256 + threadIdx.x;
        int ch = e & 63, p = e >> 6;
        d[(size_t)(px0 + p) * 64 + ch] = tile[ch * 65 + p];
    }
}

// ---------------------------------------------------------------------------
// MFMA implicit-GEMM 3x3 conv, 16x16x32 bf16, 3-term hi/lo split.
// 128 thr = 2 waves; block = 32 couts (half) x 16 px; grid 1152.
// blockIdx: bit0 = cout half, rest = px segment. Per-wave work = one
// 16-cout out-tile over full K (same as the 256-thr version; no reduce).
// Sources INTERLEAVED [px][64ch] packed u32; optional planar fp32 addsrc.
// ---------------------------------------------------------------------------
__global__ __launch_bounds__(128) void convm_k(
    const unsigned* __restrict__ s0, const unsigned* __restrict__ s1,
    const unsigned* __restrict__ s2, int b0, int b1, int b2, int nsrc,
    const ushort_t* __restrict__ wfrag, int KCfull,
    const float* __restrict__ bias, const float* __restrict__ addsrc,
    unsigned* __restrict__ outpk, int act) {
    const int tid = threadIdx.x;
    const int lane = tid & 63;
    const int w = tid >> 6;              // 0..1
    const int h = blockIdx.x & 1;       // cout half
    const int bseg = blockIdx.x >> 1;   // px segment
    const int ot = h * 2 + w;           // global out-tile 0..3
    const int xb = (bseg % 6) * 16;
    const int y = bseg / 6;
    const int n = lane & 15;
    const int quad = lane >> 4;

    __shared__ __align__(16) ushort_t ldsH[3 * 18 * 72];
    __shared__ __align__(16) ushort_t ldsL[3 * 18 * 72];

    // staging job decode (loop-invariant): 432 jobs = 54 (r,c) x 8 octets
    int jst[4], jok[4], joff[4], jbase[4];
#pragma unroll
    for (int i = 0; i < 4; ++i) {
        int e = tid + i * 128;
        int rc = e >> 3, cg = e & 7;
        int r = rc / 18, col = rc - r * 18;
        int gy = y - 1 + r, gx = xb - 1 + col;
        jst[i] = (e < 432);
        jok[i] = jst[i] && ((unsigned)gy < 96u) && ((unsigned)gx < 96u);
        joff[i] = (gy * 96 + gx) * 64 + cg * 8;
        jbase[i] = rc * 72 + cg * 8;
    }

    f32x4 acc0, acc1;
#pragma unroll
    for (int r = 0; r < 4; ++r) { acc0[r] = 0.f; acc1[r] = 0.f; }

    const size_t hlOff = (size_t)9 * KCfull * 4 * 512;

    for (int j = 0; j < nsrc; ++j) {
        const unsigned* sv = (j == 0) ? s0 : (j == 1 ? s1 : s2);
        const int base = (j == 0) ? b0 : (j == 1 ? b1 : b2);
        __syncthreads();
#pragma unroll
        for (int i = 0; i < 4; ++i) {
            if (jst[i]) {
                u32x4 a, b;
                if (jok[i]) {
                    a = *(const u32x4*)(sv + joff[i]);
                    b = *(const u32x4*)(sv + joff[i] + 4);
                } else {
#pragma unroll
                    for (int q = 0; q < 4; ++q) { a[q] = 0; b[q] = 0; }
                }
                u32x4 H, L;
#pragma unroll
                for (int q = 0; q < 2; ++q) {
                    H[q] = (a[2 * q] >> 16) | (a[2 * q + 1] & 0xFFFF0000u);
                    L[q] = (a[2 * q] & 0xFFFFu) | (a[2 * q + 1] << 16);
                    H[2 + q] = (b[2 * q] >> 16) | (b[2 * q + 1] & 0xFFFF0000u);
                    L[2 + q] = (b[2 * q] & 0xFFFFu) | (b[2 * q + 1] << 16);
                }
                *(u32x4*)(ldsH + jbase[i]) = H;
                *(u32x4*)(ldsL + jbase[i]) = L;
            }
        }
        __syncthreads();
        __builtin_amdgcn_s_setprio(1);
#pragma unroll
        for (int t = 0; t < 9; ++t) {
            const int ky = t / 3, kx = t % 3;
#pragma unroll
            for (int cc2 = 0; cc2 < 2; ++cc2) {
                const int ccor = base + cc2;
                const ushort_t* ab =
                    wfrag + (((size_t)(t * KCfull + ccor) * 4 + ot) * 64 + lane) * 8;
                bf16x8 Ah = *(const bf16x8*)ab;
                bf16x8 Al = *(const bf16x8*)(ab + hlOff);
                int lb = (ky * 18 + n + kx) * 72 + cc2 * 32 + quad * 8;
                bf16x8 Bh = *(const bf16x8*)(ldsH + lb);
                bf16x8 Bl = *(const bf16x8*)(ldsL + lb);
                if (t & 1) {
                    acc1 = __builtin_amdgcn_mfma_f32_16x16x32_bf16(Ah, Bh, acc1, 0, 0, 0);
                    acc1 = __builtin_amdgcn_mfma_f32_16x16x32_bf16(Al, Bh, acc1, 0, 0, 0);
                    acc1 = __builtin_amdgcn_mfma_f32_16x16x32_bf16(Ah, Bl, acc1, 0, 0, 0);
                } else {
                    acc0 = __builtin_amdgcn_mfma_f32_16x16x32_bf16(Ah, Bh, acc0, 0, 0, 0);
                    acc0 = __builtin_amdgcn_mfma_f32_16x16x32_bf16(Al, Bh, acc0, 0, 0, 0);
                    acc0 = __builtin_amdgcn_mfma_f32_16x16x32_bf16(Ah, Bl, acc0, 0, 0, 0);
                }
            }
        }
        __builtin_amdgcn_s_setprio(0);
    }

    const int px = y * 96 + xb + n;
#pragma unroll
    for (int r = 0; r < 4; ++r) {
        int cout = ot * 16 + quad * 4 + r;
        float v = acc0[r] + acc1[r] + bias[cout];
        if (act) v = (v >= 0.f) ? v : 0.1f * v;
        if (addsrc) v += addsrc[(size_t)cout * HW96 + px];
        outpk[(size_t)px * 64 + cout] = pk(v);
    }
}

// ---------------------------------------------------------------------------
// Fused ow4 (64->432 conv) + modulated deformable conv v2.
// 256 thr = 4 waves (reverted round-0 structure + setprio).
// Phase 1: stage hA 3x18x64 window (hi/lo) in LDS.
// Phase 2: MFMA raw[448][16] (ow4) -> LDS fp32 (stride 17: conflict-free).
// Phase 3: gather (2 u32x4 per corner) -> cols -> dconv MFMA.
// Outputs: planar fp32 (bw2 addsrc) + interleaved packed (bw1 / next gather).
// ---------------------------------------------------------------------------
__global__ __launch_bounds__(256) void dconv_fused_k(
    const unsigned* __restrict__ sA, const unsigned* __restrict__ sB,
    const unsigned* __restrict__ hA, const ushort_t* __restrict__ w4,
    const float* __restrict__ ob4, const ushort_t* __restrict__ dwf,
    const float* __restrict__ dbias, int ngr4, float* __restrict__ outf,
    unsigned* __restrict__ outpk) {
    const int tid = threadIdx.x;
    const int lane = tid & 63;
    const int w = tid >> 6;
    const int xb = (blockIdx.x % 6) * 16;
    const int y = blockIdx.x / 6;
    const int n = lane & 15;
    const int quad = lane >> 4;

    __shared__ __align__(16) char smem[18944 + 448 * 17 * 4];
    ushort_t* ldsAH = (ushort_t*)smem;        // 3888 ushorts
    ushort_t* ldsAL = ldsAH + 3888;
    ushort_t* colsH = (ushort_t*)smem;        // 16*296 ushorts (union)
    ushort_t* colsL = colsH + 4736;
    float* rawS = (float*)(smem + 18944);     // [448][17] fp32

    // ---- phase 1: stage hA window (interleaved source) ----
#pragma unroll
    for (int i = 0; i < 2; ++i) {
        int e = tid + i * 256;
        if (e < 432) {
            int rc = e >> 3, cg = e & 7;
            int r = rc / 18, col = rc - r * 18;
            int gy = y - 1 + r, gx = xb - 1 + col;
            bool ok = ((unsigned)gy < 96u) && ((unsigned)gx < 96u);
            u32x4 a, b;
            if (ok) {
                int off = (gy * 96 + gx) * 64 + cg * 8;
                a = *(const u32x4*)(hA + off);
                b = *(const u32x4*)(hA + off + 4);
            } else {
#pragma unroll
                for (int q = 0; q < 4; ++q) { a[q] = 0; b[q] = 0; }
            }
            u32x4 H, L;
#pragma unroll
            for (int q = 0; q < 2; ++q) {
                H[q] = (a[2 * q] >> 16) | (a[2 * q + 1] & 0xFFFF0000u);
                L[q] = (a[2 * q] & 0xFFFFu) | (a[2 * q + 1] << 16);
                H[2 + q] = (b[2 * q] >> 16) | (b[2 * q + 1] & 0xFFFF0000u);
                L[2 + q] = (b[2 * q] & 0xFFFFu) | (b[2 * q + 1] << 16);
            }
            *(u32x4*)(ldsAH + rc * 72 + cg * 8) = H;
            *(u32x4*)(ldsAL + rc * 72 + cg * 8) = L;
        }
    }
    __syncthreads();

    // ---- phase 2: raw = ow4(hA), 7 out-tiles per wave ----
    const size_t hl4 = (size_t)9 * 2 * 28 * 512;
#pragma unroll 1
    for (int j = 0; j < 7; ++j) {
        const int ot = j * 4 + w;
        f32x4 a0, a1;
#pragma unroll
        for (int r = 0; r < 4; ++r) { a0[r] = 0.f; a1[r] = 0.f; }
        __builtin_amdgcn_s_setprio(1);
#pragma unroll
        for (int t = 0; t < 9; ++t) {
            const int ky = t / 3, kx = t % 3;
#pragma unroll
            for (int cc2 = 0; cc2 < 2; ++cc2) {
                const ushort_t* ab =
                    w4 + (((size_t)(t * 2 + cc2) * 28 + ot) * 64 + lane) * 8;
                bf16x8 Ah = *(const bf16x8*)ab;
                bf16x8 Al = *(const bf16x8*)(ab + hl4);
                int lb = (ky * 18 + n + kx) * 72 + cc2 * 32 + quad * 8;
                bf16x8 Bh = *(const bf16x8*)(ldsAH + lb);
                bf16x8 Bl = *(const bf16x8*)(ldsAL + lb);
                if ((t * 2 + cc2) & 1) {
                    a1 = __builtin_amdgcn_mfma_f32_16x16x32_bf16(Ah, Bh, a1, 0, 0, 0);
                    a1 = __builtin_amdgcn_mfma_f32_16x16x32_bf16(Al, Bh, a1, 0, 0, 0);
                    a1 = __builtin_amdgcn_mfma_f32_16x16x32_bf16(Ah, Bl, a1, 0, 0, 0);
                } else {
                    a0 = __builtin_amdgcn_mfma_f32_16x16x32_bf16(Ah, Bh, a0, 0, 0, 0);
                    a0 = __builtin_amdgcn_mfma_f32_16x16x32_bf16(Al, Bh, a0, 0, 0, 0);
                    a0 = __builtin_amdgcn_mfma_f32_16x16x32_bf16(Ah, Bl, a0, 0, 0, 0);
                }
            }
        }
        __builtin_amdgcn_s_setprio(0);
#pragma unroll
        for (int r = 0; r < 4; ++r) {
            int cout = ot * 16 + quad * 4 + r;
            float v = a0[r] + a1[r] + (cout < 432 ? ob4[cout] : 0.f);
            rawS[cout * 17 + n] = v;
        }
    }

    // ---- phase 3: gather + dconv MFMA ----
    f32x4 acc0, acc1;
#pragma unroll
    for (int r = 0; r < 4; ++r) { acc0[r] = 0.f; acc1[r] = 0.f; }
    const size_t hlD = (size_t)36 * 4 * 512;

    for (int gc = 0; gc < ngr4; ++gc) {
        __syncthreads();  // rawS ready / cols reuse safe
#pragma unroll
        for (int i = 0; i < 3; ++i) {
            int e = tid + i * 256;
            if (e < 576) {
                int p = e & 15;
                int r = e >> 4;  // 0..35
                int gl = r / 9, k = r - gl * 9;
                int g = gc * 4 + gl;
                float ry = rawS[(g * 18 + k * 2 + 0) * 17 + p];
                float rx = rawS[(g * 18 + k * 2 + 1) * 17 + p];
                float rm = rawS[(288 + g * 9 + k) * 17 + p];
                float oy = 5.f * (1.f - 2.f / (1.f + __expf(2.f * ry)));
                float ox = 5.f * (1.f - 2.f / (1.f + __expf(2.f * rx)));
                float m = 1.f / (1.f + __expf(-rm));
                float sy = oy + (float)(y - 1 + k / 3);
                float sx = ox + (float)(xb + p - 1 + k % 3);
                float fy0 = floorf(sy), fx0 = floorf(sx);
                float fy = sy - fy0, fx = sx - fx0;
                int y0 = (int)fy0, x0 = (int)fx0;
                int y1 = y0 + 1, x1 = x0 + 1;
                bool vy0 = (unsigned)y0 < 96u, vy1 = (unsigned)y1 < 96u;
                bool vx0 = (unsigned)x0 < 96u, vx1 = (unsigned)x1 < 96u;
                int cy0 = min(max(y0, 0), 95), cy1 = min(max(y1, 0), 95);
                int cx0 = min(max(x0, 0), 95), cx1 = min(max(x1, 0), 95);
                float w00 = (1.f - fy) * (1.f - fx) * ((vy0 && vx0) ? 1.f : 0.f);
                float w01 = (1.f - fy) * fx * ((vy0 && vx1) ? 1.f : 0.f);
                float w10 = fy * (1.f - fx) * ((vy1 && vx0) ? 1.f : 0.f);
                float w11 = fy * fx * ((vy1 && vx1) ? 1.f : 0.f);
                const unsigned* src = (g < 8) ? sA : sB;
                int cb = (g & 7) * 8;
                int kbase = p * 296 + gl * 72 + k * 8;
                ushort_t hh[8], ll[8];
                if (src) {
                    int b00 = (cy0 * 96 + cx0) * 64 + cb;
                    int b01 = (cy0 * 96 + cx1) * 64 + cb;
                    int b10 = (cy1 * 96 + cx0) * 64 + cb;
                    int b11 = (cy1 * 96 + cx1) * 64 + cb;
                    u32x4 c00a = *(const u32x4*)(src + b00);
                    u32x4 c00b = *(const u32x4*)(src + b00 + 4);
                    u32x4 c01a = *(const u32x4*)(src + b01);
                    u32x4 c01b = *(const u32x4*)(src + b01 + 4);
                    u32x4 c10a = *(const u32x4*)(src + b10);
                    u32x4 c10b = *(const u32x4*)(src + b10 + 4);
                    u32x4 c11a = *(const u32x4*)(src + b11);
                    u32x4 c11b = *(const u32x4*)(src + b11 + 4);
#pragma unroll
                    for (int c = 0; c < 4; ++c) {
                        float v = w00 * unpk(c00a[c]) + w01 * unpk(c01a[c]) +
                                  w10 * unpk(c10a[c]) + w11 * unpk(c11a[c]);
                        split16(v * m, hh[c], ll[c]);
                        float v2 = w00 * unpk(c00b[c]) + w01 * unpk(c01b[c]) +
                                   w10 * unpk(c10b[c]) + w11 * unpk(c11b[c]);
                        split16(v2 * m, hh[4 + c], ll[4 + c]);
                    }
                } else {
#pragma unroll
                    for (int c = 0; c < 8; ++c) { hh[c] = 0; ll[c] = 0; }
                }
                u32x4 H, L;
#pragma unroll
                for (int q = 0; q < 4; ++q) {
                    H[q] = (unsigned)hh[2 * q] | ((unsigned)hh[2 * q + 1] << 16);
                    L[q] = (unsigned)ll[2 * q] | ((unsigned)ll[2 * q + 1] << 16);
                }
                *(u32x4*)(colsH + kbase) = H;
                *(u32x4*)(colsL + kbase) = L;
            }
        }
        __syncthreads();
        __builtin_amdgcn_s_setprio(1);
#pragma unroll
        for (int cc2 = 0; cc2 < 9; ++cc2) {
            int cc = gc * 9 + cc2;
            const ushort_t* ab = dwf + (((size_t)cc * 4 + w) * 64 + lane) * 8;
            bf16x8 Ah = *(const bf16x8*)ab;
            bf16x8 Al = *(const bf16x8*)(ab + hlD);
            int lb = n * 296 + cc2 * 32 + quad * 8;
            bf16x8 Bh = *(const bf16x8*)(colsH + lb);
            bf16x8 Bl = *(const bf16x8*)(colsL + lb);
            if (cc2 & 1) {
                acc1 = __builtin_amdgcn_mfma_f32_16x16x32_bf16(Ah, Bh, acc1, 0, 0, 0);
                acc1 = __builtin_amdgcn_mfma_f32_16x16x32_bf16(Al, Bh, acc1, 0, 0, 0);
                acc1 = __builtin_amdgcn_mfma_f32_16x16x32_bf16(Ah, Bl, acc1, 0, 0, 0);
            } else {
                acc0 = __builtin_amdgcn_mfma_f32_16x16x32_bf16(Ah, Bh, acc0, 0, 0, 0);
                acc0 = __builtin_amdgcn_mfma_f32_16x16x32_bf16(Al, Bh, acc0, 0, 0, 0);
                acc0 = __builtin_amdgcn_mfma_f32_16x16x32_bf16(Ah, Bl, acc0, 0, 0, 0);
            }
        }
        __builtin_amdgcn_s_setprio(0);
    }

    const int pidx = y * 96 + xb + n;
#pragma unroll
    for (int r = 0; r < 4; ++r) {
        int cout = w * 16 + quad * 4 + r;
        float v = acc0[r] + acc1[r] + dbias[cout];
        outf[(size_t)cout * HW96 + pidx] = v;
        outpk[(size_t)pidx * 64 + cout] = pk(v);
    }
}

// ---------------------------------------------------------------------------
// Fusion: 1x1 conv over [featB[t], featF[t]] (interleaved) + bias + x.
// ---------------------------------------------------------------------------
__global__ __launch_bounds__(256) void fuse_k(
    const unsigned* __restrict__ featB, const unsigned* __restrict__ featF,
    const float* __restrict__ x, const float* __restrict__ wp,
    const float* __restrict__ bias, float* __restrict__ out) {
    const int tx = threadIdx.x & 31;
    const int ty = threadIdx.x >> 5;
    const int px = blockIdx.x * 32 + tx;
    const int py = blockIdx.y * 8 + ty;
    const int t = blockIdx.z >> 3;
    const int obase = (blockIdx.z & 7) * 8;
    const int pidx = py * 96 + px;
    const unsigned* fB = featB + (size_t)t * FRAME + (size_t)pidx * 64;
    const unsigned* fF = featF + (size_t)t * FRAME + (size_t)pidx * 64;

    float acc[8];
#pragma unroll
    for (int o = 0; o < 8; ++o) acc[o] = 0.f;

#pragma unroll 4
    for (int i0 = 0; i0 < 64; i0 += 4) {
        u32x4 pv = *(const u32x4*)(fB + i0);
#pragma unroll
        for (int q = 0; q < 4; ++q) {
            float v = unpk(pv[q]);
            const float* wr = wp + (i0 + q) * 64 + obase;
#pragma unroll
            for (int o = 0; o < 8; ++o) acc[o] = fmaf(wr[o], v, acc[o]);
        }
    }
#pragma unroll 4
    for (int i0 = 0; i0 < 64; i0 += 4) {
        u32x4 pv = *(const u32x4*)(fF + i0);
#pragma unroll
        for (int q = 0; q < 4; ++q) {
            float v = unpk(pv[q]);
            const float* wr = wp + (64 + i0 + q) * 64 + obase;
#pragma unroll
            for (int o = 0; o < 8; ++o) acc[o] = fmaf(wr[o], v, acc[o]);
        }
    }
    const float* xt = x + (size_t)t * FRAME;
#pragma unroll
    for (int o = 0; o < 8; ++o)
        out[(size_t)t * FRAME + (size_t)(obase + o) * HW96 + pidx] =
            acc[o] + bias[obase + o] + xt[(size_t)(obase + o) * HW96 + pidx];
}

// ---------------------------------------------------------------------------
extern "C" void kernel_launch(void* const* d_in, const int* in_sizes, int n_in,
                              void* d_out, int out_size, void* d_ws,
                              size_t ws_size, hipStream_t stream) {
    const float* x = (const float*)d_in[0];
    auto gp = [&](int i) { return (const float*)d_in[i]; };

    struct DirP {
        const float *dw, *db, *ow1, *ob1, *ow2, *ob2, *ow3, *ob3, *ow4, *ob4,
            *bw1, *bb1, *bw2, *bb2;
    };
    DirP Pb{gp(1), gp(2), gp(3), gp(4), gp(5), gp(6), gp(7),
            gp(8), gp(9), gp(10), gp(11), gp(12), gp(13), gp(14)};
    DirP Pf{gp(15), gp(16), gp(17), gp(18), gp(19), gp(20), gp(21),
            gp(22), gp(23), gp(24), gp(25), gp(26), gp(27), gp(28)};
    const float* fus_w = gp(29);
    const float* fus_b = gp(30);

    // ---- workspace carve-up (4-byte units); all feature bufs interleaved ----
    unsigned* featBpk = (unsigned*)d_ws;
    unsigned* featFpk = featBpk + (size_t)8 * FRAME;
    unsigned* xpk = featFpk + (size_t)8 * FRAME;
    float* Dbuf = (float*)(xpk + (size_t)8 * FRAME);  // planar fp32
    unsigned* Dpk = (unsigned*)(Dbuf + FRAME);        // interleaved packed
    unsigned* hApk = Dpk + FRAME;
    unsigned* hBpk = hApk + FRAME;
    float* wfus = (float*)(hBpk + FRAME);
    ushort_t* fragp = (ushort_t*)(wfus + 128 * 64);

    auto falloc = [&](size_t nelem) {
        ushort_t* p = fragp;
        fragp += nelem;
        return p;
    };

    // ---- weight prep ----
    repack_fus_k<<<32, 256, 0, stream>>>(fus_w, wfus);

    struct DirW { ushort_t *ow1, *ow2, *ow3, *ow4, *bw1, *bw2, *dw; int bw1KC; };
    FragJobs fj;
    int nf = 0;
    auto fjob = [&](const float* src, int O, int I, int OT, int KC) {
        ushort_t* dst = falloc((size_t)2 * 9 * KC * OT * 512);
        fj.j[nf++] = FragJob{src, dst, O, I, OT, KC, 0};
        return dst;
    };
    auto fjobd = [&](const float* src) {
        ushort_t* dst = falloc((size_t)2 * 36 * 4 * 512);
        fj.j[nf++] = FragJob{src, dst, 64, 128, 4, 36, 1};
        return dst;
    };
    DirW Wb, Wf;
    Wb.ow1 = fjob(Pb.ow1, 64, 192, 4, 6);
    Wb.ow2 = fjob(Pb.ow2, 64, 64, 4, 2);
    Wb.ow3 = fjob(Pb.ow3, 64, 64, 4, 2);
    Wb.ow4 = fjob(Pb.ow4, 432, 64, 28, 2);
    Wb.bw1 = fjob(Pb.bw1, 64, 128, 4, 4);
    Wb.bw1KC = 4;
    Wb.bw2 = fjob(Pb.bw2, 64, 64, 4, 2);
    Wb.dw = fjobd(Pb.dw);
    Wf.ow1 = fjob(Pf.ow1, 64, 192, 4, 6);
    Wf.ow2 = fjob(Pf.ow2, 64, 64, 4, 2);
    Wf.ow3 = fjob(Pf.ow3, 64, 64, 4, 2);
    Wf.ow4 = fjob(Pf.ow4, 432, 64, 28, 2);
    Wf.bw1 = fjob(Pf.bw1, 64, 192, 4, 6);
    Wf.bw1KC = 6;
    Wf.bw2 = fjob(Pf.bw2, 64, 64, 4, 2);
    Wf.dw = fjobd(Pf.dw);
    frag_all_k<<<dim3(1008, 14), 256, 0, stream>>>(fj);

    pack_tr_k<<<dim3(144, 8), 256, 0, stream>>>(x, xpk);

    auto convm = [&](const unsigned* a, const unsigned* b, const unsigned* c2,
                     const ushort_t* frag, int KCfull, const float* bias,
                     const float* addsrc, unsigned* out, int act) {
        const unsigned* srcs[3] = {a, b, c2};
        const unsigned* S[3] = {nullptr, nullptr, nullptr};
        int B[3] = {0, 0, 0};
        int ns = 0;
        for (int j = 0; j < 3; ++j)
            if (srcs[j]) {
                S[ns] = srcs[j];
                B[ns] = j * 2;
                ++ns;
            }
        convm_k<<<1152, 128, 0, stream>>>(S[0], S[1], S[2], B[0], B[1], B[2],
                                          ns, frag, KCfull, bias, addsrc, out,
                                          act);
    };

    for (int dir = 0; dir < 2; ++dir) {  // 0 = backward, 1 = forward
        const DirP& P = dir ? Pf : Pb;
        const DirW& W = dir ? Wf : Wb;
        unsigned* feat = dir ? featFpk : featBpk;
        const unsigned* prev1 = nullptr;
        const unsigned* prev2 = nullptr;
        for (int i = 0; i < 8; ++i) {
            int idx = dir ? i : 7 - i;
            const unsigned* cur = xpk + (size_t)idx * FRAME;
            const float* propf = nullptr;
            if (i > 0) {
                convm(prev1, cur, prev2, W.ow1, 6, P.ob1, nullptr, hApk, 1);
                convm(hApk, nullptr, nullptr, W.ow2, 2, P.ob2, nullptr, hBpk, 1);
                convm(hBpk, nullptr, nullptr, W.ow3, 2, P.ob3, nullptr, hApk, 1);
                int ngr4 = (prev2 != nullptr) ? 4 : 2;
                dconv_fused_k<<<576, 256, 0, stream>>>(
                    prev1, prev2, hApk, W.ow4, P.ob4, W.dw, P.db, ngr4, Dbuf,
                    Dpk);
                propf = Dbuf;
            }
            unsigned* dst = feat + (size_t)idx * FRAME;
            if (dir == 0) {
                convm(cur, (i > 0) ? Dpk : nullptr, nullptr, W.bw1, W.bw1KC,
                      P.bb1, nullptr, hBpk, 1);
            } else {
                convm(cur, featBpk + (size_t)idx * FRAME,
                      (i > 0) ? Dpk : nullptr, W.bw1, W.bw1KC, P.bb1, nullptr,
                      hBpk, 1);
            }
            convm(hBpk, nullptr, nullptr, W.bw2, 2, P.bb2, propf, dst, 0);
            prev2 = prev1;
            prev1 = dst;
        }
    }

    fuse_k<<<dim3(3, 12, 64), 256, 0, stream>>>(featBpk, featFpk, x, wfus,
                                                fus_b, (float*)d_out);
}

// Round 4
// 1842.397 us; speedup vs baseline: 1.1942x; 1.0253x over previous
//
#include <hip/hip_runtime.h>
#include <cstddef>

#define HW96 9216
#define FRAME (64 * 9216)

typedef unsigned short ushort_t;
typedef __attribute__((ext_vector_type(8))) short bf16x8;
typedef __attribute__((ext_vector_type(4))) float f32x4;
typedef __attribute__((ext_vector_type(4))) unsigned u32x4;

// packed u32 = (bf16 hi bits << 16) | bf16 lo bits; value = hi + lo exactly
__device__ __forceinline__ float unpk(unsigned p) {
    return __uint_as_float(p & 0xFFFF0000u) + __uint_as_float(p << 16);
}
__device__ __forceinline__ unsigned pk(float v) {
    unsigned u = __float_as_uint(v);
    unsigned hi = u & 0xFFFF0000u;
    float rem = v - __uint_as_float(hi);
    unsigned r = __float_as_uint(rem);
    unsigned lo = (r + 0x7FFFu + ((r >> 16) & 1u)) >> 16;
    return hi | (lo & 0xFFFFu);
}
__device__ __forceinline__ void split16(float v, ushort_t& h, ushort_t& l) {
    unsigned u = __float_as_uint(v);
    h = (ushort_t)(u >> 16);
    float rem = v - __uint_as_float(u & 0xFFFF0000u);
    unsigned r = __float_as_uint(rem);
    l = (ushort_t)((r + 0x7FFFu + ((r >> 16) & 1u)) >> 16);
}

// ---------------------------------------------------------------------------
// Plain repack: OIHW -> [i][o] fp32 (fusion 1x1 only).
// ---------------------------------------------------------------------------
__global__ __launch_bounds__(256) void repack_fus_k(const float* __restrict__ w,
                                                    float* __restrict__ wp) {
    int idx = blockIdx.x * 256 + threadIdx.x;  // 128*64
    if (idx >= 128 * 64) return;
    int o = idx % 64;
    int i = idx / 64;
    wp[idx] = w[o * 128 + i];
}

// ---------------------------------------------------------------------------
// MFMA A-fragment prepack (16x16x32) with bf16 hi/lo split.
// mode 0 (3x3 conv): layout [hl][t][cc][ot][lane][j]; K = cin chunks of 32.
// mode 1 (dconv):    layout [hl][cc][ot][lane][j]; K = g*72 + tap*8 + c.
// A[m=lane&15][k=(lane>>4)*8+j].
// ---------------------------------------------------------------------------
struct FragJob { const float* src; ushort_t* dst; int O, I, OT, KC, mode; };
struct FragJobs { FragJob j[14]; };

__global__ __launch_bounds__(256) void frag_all_k(FragJobs jobs) {
    const FragJob& J = jobs.j[blockIdx.y];
    int idx = blockIdx.x * 256 + threadIdx.x;
    int total = (J.mode ? 1 : 9) * J.KC * J.OT * 512;
    if (idx >= total) return;
    int jj = idx & 7;
    int lane = (idx >> 3) & 63;
    int rem = idx >> 9;
    int ot = rem % J.OT;
    rem /= J.OT;
    int cc = rem % J.KC;
    int t = rem / J.KC;
    int o = ot * 16 + (lane & 15);
    float wv = 0.f;
    if (J.mode == 0) {
        int ci = cc * 32 + (lane >> 4) * 8 + jj;
        if (o < J.O && ci < J.I) wv = J.src[(o * J.I + ci) * 9 + t];
    } else {
        int K = cc * 32 + (lane >> 4) * 8 + jj;
        int g = K / 72, r2 = K % 72;
        int tap = r2 >> 3, c = r2 & 7;
        int ci = g * 8 + c;
        if (o < J.O && ci < J.I) wv = J.src[(o * J.I + ci) * 9 + tap];
    }
    ushort_t h, l;
    split16(wv, h, l);
    J.dst[idx] = h;
    J.dst[total + idx] = l;
}

// ---------------------------------------------------------------------------
// Transposing pack: planar fp32 frames -> interleaved [px][64ch] packed u32.
// Block handles one 64-px x 64-ch tile via padded LDS. grid (144, T).
// ---------------------------------------------------------------------------
__global__ __launch_bounds__(256) void pack_tr_k(const float* __restrict__ src,
                                                 unsigned* __restrict__ dst) {
    const int t = blockIdx.y;
    const int px0 = blockIdx.x * 64;
    __shared__ unsigned tile[64 * 65];
    const float* s = src + (size_t)t * FRAME;
    unsigned* d = dst + (size_t)t * FRAME;
#pragma unroll
    for (int it = 0; it < 16; ++it) {
        int e = it * 256 + threadIdx.x;
        int p = e & 63, ch = e >> 6;
        tile[ch * 65 + p] = pk(s[(size_t)ch * HW96 + px0 + p]);
    }
    __syncthreads();
#pragma unroll
    for (int it = 0; it < 16; ++it) {
        int e = it * 256 + threadIdx.x;
        int ch = e & 63, p = e >> 6;
        d[(size_t)(px0 + p) * 64 + ch] = tile[ch * 65 + p];
    }
}

// ---------------------------------------------------------------------------
// MFMA implicit-GEMM 3x3 conv, 16x16x32 bf16, 3-term hi/lo split.
// 128 thr = 2 waves; block = 32 couts (half) x 16 px; grid 1152.
// Rolling depth-5 software pipeline over the 18 (t,cc2) steps per source.
// Ring discipline: CONSUME u=s-5 FIRST, then load fragment s into slot s%5
// (ring size == depth requires drain-before-fill; round-3 bug was reversed).
// ---------------------------------------------------------------------------
__global__ __launch_bounds__(128, 3) void convm_k(
    const unsigned* __restrict__ s0, const unsigned* __restrict__ s1,
    const unsigned* __restrict__ s2, int b0, int b1, int b2, int nsrc,
    const ushort_t* __restrict__ wfrag, int KCfull,
    const float* __restrict__ bias, const float* __restrict__ addsrc,
    unsigned* __restrict__ outpk, int act) {
    const int tid = threadIdx.x;
    const int lane = tid & 63;
    const int w = tid >> 6;              // 0..1
    const int h = blockIdx.x & 1;       // cout half
    const int bseg = blockIdx.x >> 1;   // px segment
    const int ot = h * 2 + w;           // global out-tile 0..3
    const int xb = (bseg % 6) * 16;
    const int y = bseg / 6;
    const int n = lane & 15;
    const int quad = lane >> 4;

    __shared__ __align__(16) ushort_t ldsH[3 * 18 * 72];
    __shared__ __align__(16) ushort_t ldsL[3 * 18 * 72];

    // staging job decode (loop-invariant): 432 jobs = 54 (r,c) x 8 octets
    int jst[4], jok[4], joff[4], jbase[4];
#pragma unroll
    for (int i = 0; i < 4; ++i) {
        int e = tid + i * 128;
        int rc = e >> 3, cg = e & 7;
        int r = rc / 18, col = rc - r * 18;
        int gy = y - 1 + r, gx = xb - 1 + col;
        jst[i] = (e < 432);
        jok[i] = jst[i] && ((unsigned)gy < 96u) && ((unsigned)gx < 96u);
        joff[i] = (gy * 96 + gx) * 64 + cg * 8;
        jbase[i] = rc * 72 + cg * 8;
    }

    f32x4 acc0, acc1;
#pragma unroll
    for (int r = 0; r < 4; ++r) { acc0[r] = 0.f; acc1[r] = 0.f; }

    const size_t hlOff = (size_t)9 * KCfull * 4 * 512;

    for (int j = 0; j < nsrc; ++j) {
        const unsigned* sv = (j == 0) ? s0 : (j == 1 ? s1 : s2);
        const int base = (j == 0) ? b0 : (j == 1 ? b1 : b2);
        __syncthreads();
#pragma unroll
        for (int i = 0; i < 4; ++i) {
            if (jst[i]) {
                u32x4 a, b;
                if (jok[i]) {
                    a = *(const u32x4*)(sv + joff[i]);
                    b = *(const u32x4*)(sv + joff[i] + 4);
                } else {
#pragma unroll
                    for (int q = 0; q < 4; ++q) { a[q] = 0; b[q] = 0; }
                }
                u32x4 H, L;
#pragma unroll
                for (int q = 0; q < 2; ++q) {
                    H[q] = (a[2 * q] >> 16) | (a[2 * q + 1] & 0xFFFF0000u);
                    L[q] = (a[2 * q] & 0xFFFFu) | (a[2 * q + 1] << 16);
                    H[2 + q] = (b[2 * q] >> 16) | (b[2 * q + 1] & 0xFFFF0000u);
                    L[2 + q] = (b[2 * q] & 0xFFFFu) | (b[2 * q + 1] << 16);
                }
                *(u32x4*)(ldsH + jbase[i]) = H;
                *(u32x4*)(ldsL + jbase[i]) = L;
            }
        }
        __syncthreads();
        // depth-5 rolling pipeline over 18 steps (t = s>>1, cc2 = s&1)
        bf16x8 pAh[5], pAl[5], pBh[5], pBl[5];
#pragma unroll
        for (int s = 0; s < 23; ++s) {
            if (s >= 5) {  // consume BEFORE refilling the slot
                const int u = s - 5;
                const bf16x8 Ah = pAh[u % 5], Al = pAl[u % 5];
                const bf16x8 Bh = pBh[u % 5], Bl = pBl[u % 5];
                if (u & 1) {
                    acc1 = __builtin_amdgcn_mfma_f32_16x16x32_bf16(Ah, Bh, acc1, 0, 0, 0);
                    acc1 = __builtin_amdgcn_mfma_f32_16x16x32_bf16(Al, Bh, acc1, 0, 0, 0);
                    acc1 = __builtin_amdgcn_mfma_f32_16x16x32_bf16(Ah, Bl, acc1, 0, 0, 0);
                } else {
                    acc0 = __builtin_amdgcn_mfma_f32_16x16x32_bf16(Ah, Bh, acc0, 0, 0, 0);
                    acc0 = __builtin_amdgcn_mfma_f32_16x16x32_bf16(Al, Bh, acc0, 0, 0, 0);
                    acc0 = __builtin_amdgcn_mfma_f32_16x16x32_bf16(Ah, Bl, acc0, 0, 0, 0);
                }
            }
            if (s < 18) {
                const int t = s >> 1, cc2 = s & 1;
                const int ky = t / 3, kx = t % 3;
                const int ccor = base + cc2;
                const ushort_t* ab =
                    wfrag + (((size_t)(t * KCfull + ccor) * 4 + ot) * 64 + lane) * 8;
                pAh[s % 5] = *(const bf16x8*)ab;
                pAl[s % 5] = *(const bf16x8*)(ab + hlOff);
                const int lb = (ky * 18 + n + kx) * 72 + cc2 * 32 + quad * 8;
                pBh[s % 5] = *(const bf16x8*)(ldsH + lb);
                pBl[s % 5] = *(const bf16x8*)(ldsL + lb);
            }
        }
    }

    const int px = y * 96 + xb + n;
#pragma unroll
    for (int r = 0; r < 4; ++r) {
        int cout = ot * 16 + quad * 4 + r;
        float v = acc0[r] + acc1[r] + bias[cout];
        if (act) v = (v >= 0.f) ? v : 0.1f * v;
        if (addsrc) v += addsrc[(size_t)cout * HW96 + px];
        outpk[(size_t)px * 64 + cout] = pk(v);
    }
}

// ---------------------------------------------------------------------------
// Fused ow4 (64->432 conv) + modulated deformable conv v2.
// 256 thr = 4 waves. Phase 2 and phase-3-MFMA use rolling register
// pipelines (depth 5 / 4), consume-before-fill ring discipline.
// ---------------------------------------------------------------------------
__global__ __launch_bounds__(256, 3) void dconv_fused_k(
    const unsigned* __restrict__ sA, const unsigned* __restrict__ sB,
    const unsigned* __restrict__ hA, const ushort_t* __restrict__ w4,
    const float* __restrict__ ob4, const ushort_t* __restrict__ dwf,
    const float* __restrict__ dbias, int ngr4, float* __restrict__ outf,
    unsigned* __restrict__ outpk) {
    const int tid = threadIdx.x;
    const int lane = tid & 63;
    const int w = tid >> 6;
    const int xb = (blockIdx.x % 6) * 16;
    const int y = blockIdx.x / 6;
    const int n = lane & 15;
    const int quad = lane >> 4;

    __shared__ __align__(16) char smem[18944 + 448 * 17 * 4];
    ushort_t* ldsAH = (ushort_t*)smem;        // 3888 ushorts
    ushort_t* ldsAL = ldsAH + 3888;
    ushort_t* colsH = (ushort_t*)smem;        // 16*296 ushorts (union)
    ushort_t* colsL = colsH + 4736;
    float* rawS = (float*)(smem + 18944);     // [448][17] fp32

    // ---- phase 1: stage hA window (interleaved source) ----
#pragma unroll
    for (int i = 0; i < 2; ++i) {
        int e = tid + i * 256;
        if (e < 432) {
            int rc = e >> 3, cg = e & 7;
            int r = rc / 18, col = rc - r * 18;
            int gy = y - 1 + r, gx = xb - 1 + col;
            bool ok = ((unsigned)gy < 96u) && ((unsigned)gx < 96u);
            u32x4 a, b;
            if (ok) {
                int off = (gy * 96 + gx) * 64 + cg * 8;
                a = *(const u32x4*)(hA + off);
                b = *(const u32x4*)(hA + off + 4);
            } else {
#pragma unroll
                for (int q = 0; q < 4; ++q) { a[q] = 0; b[q] = 0; }
            }
            u32x4 H, L;
#pragma unroll
            for (int q = 0; q < 2; ++q) {
                H[q] = (a[2 * q] >> 16) | (a[2 * q + 1] & 0xFFFF0000u);
                L[q] = (a[2 * q] & 0xFFFFu) | (a[2 * q + 1] << 16);
                H[2 + q] = (b[2 * q] >> 16) | (b[2 * q + 1] & 0xFFFF0000u);
                L[2 + q] = (b[2 * q] & 0xFFFFu) | (b[2 * q + 1] << 16);
            }
            *(u32x4*)(ldsAH + rc * 72 + cg * 8) = H;
            *(u32x4*)(ldsAL + rc * 72 + cg * 8) = L;
        }
    }
    __syncthreads();

    // ---- phase 2: raw = ow4(hA), 7 out-tiles per wave, depth-5 pipeline ----
    const size_t hl4 = (size_t)9 * 2 * 28 * 512;
#pragma unroll 1
    for (int j = 0; j < 7; ++j) {
        const int ot = j * 4 + w;
        f32x4 a0, a1;
#pragma unroll
        for (int r = 0; r < 4; ++r) { a0[r] = 0.f; a1[r] = 0.f; }
        bf16x8 pAh[5], pAl[5], pBh[5], pBl[5];
#pragma unroll
        for (int s = 0; s < 23; ++s) {
            if (s >= 5) {  // consume BEFORE refilling the slot
                const int u = s - 5;
                const bf16x8 Ah = pAh[u % 5], Al = pAl[u % 5];
                const bf16x8 Bh = pBh[u % 5], Bl = pBl[u % 5];
                if (u & 1) {
                    a1 = __builtin_amdgcn_mfma_f32_16x16x32_bf16(Ah, Bh, a1, 0, 0, 0);
                    a1 = __builtin_amdgcn_mfma_f32_16x16x32_bf16(Al, Bh, a1, 0, 0, 0);
                    a1 = __builtin_amdgcn_mfma_f32_16x16x32_bf16(Ah, Bl, a1, 0, 0, 0);
                } else {
                    a0 = __builtin_amdgcn_mfma_f32_16x16x32_bf16(Ah, Bh, a0, 0, 0, 0);
                    a0 = __builtin_amdgcn_mfma_f32_16x16x32_bf16(Al, Bh, a0, 0, 0, 0);
                    a0 = __builtin_amdgcn_mfma_f32_16x16x32_bf16(Ah, Bl, a0, 0, 0, 0);
                }
            }
            if (s < 18) {
                const int t = s >> 1, cc2 = s & 1;
                const int ky = t / 3, kx = t % 3;
                const ushort_t* ab =
                    w4 + (((size_t)s * 28 + ot) * 64 + lane) * 8;
                pAh[s % 5] = *(const bf16x8*)ab;
                pAl[s % 5] = *(const bf16x8*)(ab + hl4);
                const int lb = (ky * 18 + n + kx) * 72 + cc2 * 32 + quad * 8;
                pBh[s % 5] = *(const bf16x8*)(ldsAH + lb);
                pBl[s % 5] = *(const bf16x8*)(ldsAL + lb);
            }
        }
#pragma unroll
        for (int r = 0; r < 4; ++r) {
            int cout = ot * 16 + quad * 4 + r;
            float v = a0[r] + a1[r] + (cout < 432 ? ob4[cout] : 0.f);
            rawS[cout * 17 + n] = v;
        }
    }

    // ---- phase 3: gather + dconv MFMA (depth-4 pipeline) ----
    f32x4 acc0, acc1;
#pragma unroll
    for (int r = 0; r < 4; ++r) { acc0[r] = 0.f; acc1[r] = 0.f; }
    const size_t hlD = (size_t)36 * 4 * 512;

    for (int gc = 0; gc < ngr4; ++gc) {
        __syncthreads();  // rawS ready / cols reuse safe
#pragma unroll
        for (int i = 0; i < 3; ++i) {
            int e = tid + i * 256;
            if (e < 576) {
                int p = e & 15;
                int r = e >> 4;  // 0..35
                int gl = r / 9, k = r - gl * 9;
                int g = gc * 4 + gl;
                float ry = rawS[(g * 18 + k * 2 + 0) * 17 + p];
                float rx = rawS[(g * 18 + k * 2 + 1) * 17 + p];
                float rm = rawS[(288 + g * 9 + k) * 17 + p];
                float oy = 5.f * (1.f - 2.f / (1.f + __expf(2.f * ry)));
                float ox = 5.f * (1.f - 2.f / (1.f + __expf(2.f * rx)));
                float m = 1.f / (1.f + __expf(-rm));
                float sy = oy + (float)(y - 1 + k / 3);
                float sx = ox + (float)(xb + p - 1 + k % 3);
                float fy0 = floorf(sy), fx0 = floorf(sx);
                float fy = sy - fy0, fx = sx - fx0;
                int y0 = (int)fy0, x0 = (int)fx0;
                int y1 = y0 + 1, x1 = x0 + 1;
                bool vy0 = (unsigned)y0 < 96u, vy1 = (unsigned)y1 < 96u;
                bool vx0 = (unsigned)x0 < 96u, vx1 = (unsigned)x1 < 96u;
                int cy0 = min(max(y0, 0), 95), cy1 = min(max(y1, 0), 95);
                int cx0 = min(max(x0, 0), 95), cx1 = min(max(x1, 0), 95);
                float w00 = (1.f - fy) * (1.f - fx) * ((vy0 && vx0) ? 1.f : 0.f);
                float w01 = (1.f - fy) * fx * ((vy0 && vx1) ? 1.f : 0.f);
                float w10 = fy * (1.f - fx) * ((vy1 && vx0) ? 1.f : 0.f);
                float w11 = fy * fx * ((vy1 && vx1) ? 1.f : 0.f);
                const unsigned* src = (g < 8) ? sA : sB;
                int cb = (g & 7) * 8;
                int kbase = p * 296 + gl * 72 + k * 8;
                ushort_t hh[8], ll[8];
                if (src) {
                    int b00 = (cy0 * 96 + cx0) * 64 + cb;
                    int b01 = (cy0 * 96 + cx1) * 64 + cb;
                    int b10 = (cy1 * 96 + cx0) * 64 + cb;
                    int b11 = (cy1 * 96 + cx1) * 64 + cb;
                    u32x4 c00a = *(const u32x4*)(src + b00);
                    u32x4 c00b = *(const u32x4*)(src + b00 + 4);
                    u32x4 c01a = *(const u32x4*)(src + b01);
                    u32x4 c01b = *(const u32x4*)(src + b01 + 4);
                    u32x4 c10a = *(const u32x4*)(src + b10);
                    u32x4 c10b = *(const u32x4*)(src + b10 + 4);
                    u32x4 c11a = *(const u32x4*)(src + b11);
                    u32x4 c11b = *(const u32x4*)(src + b11 + 4);
#pragma unroll
                    for (int c = 0; c < 4; ++c) {
                        float v = w00 * unpk(c00a[c]) + w01 * unpk(c01a[c]) +
                                  w10 * unpk(c10a[c]) + w11 * unpk(c11a[c]);
                        split16(v * m, hh[c], ll[c]);
                        float v2 = w00 * unpk(c00b[c]) + w01 * unpk(c01b[c]) +
                                   w10 * unpk(c10b[c]) + w11 * unpk(c11b[c]);
                        split16(v2 * m, hh[4 + c], ll[4 + c]);
                    }
                } else {
#pragma unroll
                    for (int c = 0; c < 8; ++c) { hh[c] = 0; ll[c] = 0; }
                }
                u32x4 H, L;
#pragma unroll
                for (int q = 0; q < 4; ++q) {
                    H[q] = (unsigned)hh[2 * q] | ((unsigned)hh[2 * q + 1] << 16);
                    L[q] = (unsigned)ll[2 * q] | ((unsigned)ll[2 * q + 1] << 16);
                }
                *(u32x4*)(colsH + kbase) = H;
                *(u32x4*)(colsL + kbase) = L;
            }
        }
        __syncthreads();
        bf16x8 qAh[4], qAl[4], qBh[4], qBl[4];
#pragma unroll
        for (int s = 0; s < 13; ++s) {
            if (s >= 4) {  // consume BEFORE refilling the slot
                const int u = s - 4;
                const bf16x8 Ah = qAh[u % 4], Al = qAl[u % 4];
                const bf16x8 Bh = qBh[u % 4], Bl = qBl[u % 4];
                if (u & 1) {
                    acc1 = __builtin_amdgcn_mfma_f32_16x16x32_bf16(Ah, Bh, acc1, 0, 0, 0);
                    acc1 = __builtin_amdgcn_mfma_f32_16x16x32_bf16(Al, Bh, acc1, 0, 0, 0);
                    acc1 = __builtin_amdgcn_mfma_f32_16x16x32_bf16(Ah, Bl, acc1, 0, 0, 0);
                } else {
                    acc0 = __builtin_amdgcn_mfma_f32_16x16x32_bf16(Ah, Bh, acc0, 0, 0, 0);
                    acc0 = __builtin_amdgcn_mfma_f32_16x16x32_bf16(Al, Bh, acc0, 0, 0, 0);
                    acc0 = __builtin_amdgcn_mfma_f32_16x16x32_bf16(Ah, Bl, acc0, 0, 0, 0);
                }
            }
            if (s < 9) {
                const int cc = gc * 9 + s;
                const ushort_t* ab = dwf + (((size_t)cc * 4 + w) * 64 + lane) * 8;
                qAh[s % 4] = *(const bf16x8*)ab;
                qAl[s % 4] = *(const bf16x8*)(ab + hlD);
                const int lb = n * 296 + s * 32 + quad * 8;
                qBh[s % 4] = *(const bf16x8*)(colsH + lb);
                qBl[s % 4] = *(const bf16x8*)(colsL + lb);
            }
        }
    }

    const int pidx = y * 96 + xb + n;
#pragma unroll
    for (int r = 0; r < 4; ++r) {
        int cout = w * 16 + quad * 4 + r;
        float v = acc0[r] + acc1[r] + dbias[cout];
        outf[(size_t)cout * HW96 + pidx] = v;
        outpk[(size_t)pidx * 64 + cout] = pk(v);
    }
}

// ---------------------------------------------------------------------------
// Fusion: 1x1 conv over [featB[t], featF[t]] (interleaved) + bias + x.
// ---------------------------------------------------------------------------
__global__ __launch_bounds__(256) void fuse_k(
    const unsigned* __restrict__ featB, const unsigned* __restrict__ featF,
    const float* __restrict__ x, const float* __restrict__ wp,
    const float* __restrict__ bias, float* __restrict__ out) {
    const int tx = threadIdx.x & 31;
    const int ty = threadIdx.x >> 5;
    const int px = blockIdx.x * 32 + tx;
    const int py = blockIdx.y * 8 + ty;
    const int t = blockIdx.z >> 3;
    const int obase = (blockIdx.z & 7) * 8;
    const int pidx = py * 96 + px;
    const unsigned* fB = featB + (size_t)t * FRAME + (size_t)pidx * 64;
    const unsigned* fF = featF + (size_t)t * FRAME + (size_t)pidx * 64;

    float acc[8];
#pragma unroll
    for (int o = 0; o < 8; ++o) acc[o] = 0.f;

#pragma unroll 4
    for (int i0 = 0; i0 < 64; i0 += 4) {
        u32x4 pv = *(const u32x4*)(fB + i0);
#pragma unroll
        for (int q = 0; q < 4; ++q) {
            float v = unpk(pv[q]);
            const float* wr = wp + (i0 + q) * 64 + obase;
#pragma unroll
            for (int o = 0; o < 8; ++o) acc[o] = fmaf(wr[o], v, acc[o]);
        }
    }
#pragma unroll 4
    for (int i0 = 0; i0 < 64; i0 += 4) {
        u32x4 pv = *(const u32x4*)(fF + i0);
#pragma unroll
        for (int q = 0; q < 4; ++q) {
            float v = unpk(pv[q]);
            const float* wr = wp + (64 + i0 + q) * 64 + obase;
#pragma unroll
            for (int o = 0; o < 8; ++o) acc[o] = fmaf(wr[o], v, acc[o]);
        }
    }
    const float* xt = x + (size_t)t * FRAME;
#pragma unroll
    for (int o = 0; o < 8; ++o)
        out[(size_t)t * FRAME + (size_t)(obase + o) * HW96 + pidx] =
            acc[o] + bias[obase + o] + xt[(size_t)(obase + o) * HW96 + pidx];
}

// ---------------------------------------------------------------------------
extern "C" void kernel_launch(void* const* d_in, const int* in_sizes, int n_in,
                              void* d_out, int out_size, void* d_ws,
                              size_t ws_size, hipStream_t stream) {
    const float* x = (const float*)d_in[0];
    auto gp = [&](int i) { return (const float*)d_in[i]; };

    struct DirP {
        const float *dw, *db, *ow1, *ob1, *ow2, *ob2, *ow3, *ob3, *ow4, *ob4,
            *bw1, *bb1, *bw2, *bb2;
    };
    DirP Pb{gp(1), gp(2), gp(3), gp(4), gp(5), gp(6), gp(7),
            gp(8), gp(9), gp(10), gp(11), gp(12), gp(13), gp(14)};
    DirP Pf{gp(15), gp(16), gp(17), gp(18), gp(19), gp(20), gp(21),
            gp(22), gp(23), gp(24), gp(25), gp(26), gp(27), gp(28)};
    const float* fus_w = gp(29);
    const float* fus_b = gp(30);

    // ---- workspace carve-up (4-byte units); all feature bufs interleaved ----
    unsigned* featBpk = (unsigned*)d_ws;
    unsigned* featFpk = featBpk + (size_t)8 * FRAME;
    unsigned* xpk = featFpk + (size_t)8 * FRAME;
    float* Dbuf = (float*)(xpk + (size_t)8 * FRAME);  // planar fp32
    unsigned* Dpk = (unsigned*)(Dbuf + FRAME);        // interleaved packed
    unsigned* hApk = Dpk + FRAME;
    unsigned* hBpk = hApk + FRAME;
    float* wfus = (float*)(hBpk + FRAME);
    ushort_t* fragp = (ushort_t*)(wfus + 128 * 64);

    auto falloc = [&](size_t nelem) {
        ushort_t* p = fragp;
        fragp += nelem;
        return p;
    };

    // ---- weight prep ----
    repack_fus_k<<<32, 256, 0, stream>>>(fus_w, wfus);

    struct DirW { ushort_t *ow1, *ow2, *ow3, *ow4, *bw1, *bw2, *dw; int bw1KC; };
    FragJobs fj;
    int nf = 0;
    auto fjob = [&](const float* src, int O, int I, int OT, int KC) {
        ushort_t* dst = falloc((size_t)2 * 9 * KC * OT * 512);
        fj.j[nf++] = FragJob{src, dst, O, I, OT, KC, 0};
        return dst;
    };
    auto fjobd = [&](const float* src) {
        ushort_t* dst = falloc((size_t)2 * 36 * 4 * 512);
        fj.j[nf++] = FragJob{src, dst, 64, 128, 4, 36, 1};
        return dst;
    };
    DirW Wb, Wf;
    Wb.ow1 = fjob(Pb.ow1, 64, 192, 4, 6);
    Wb.ow2 = fjob(Pb.ow2, 64, 64, 4, 2);
    Wb.ow3 = fjob(Pb.ow3, 64, 64, 4, 2);
    Wb.ow4 = fjob(Pb.ow4, 432, 64, 28, 2);
    Wb.bw1 = fjob(Pb.bw1, 64, 128, 4, 4);
    Wb.bw1KC = 4;
    Wb.bw2 = fjob(Pb.bw2, 64, 64, 4, 2);
    Wb.dw = fjobd(Pb.dw);
    Wf.ow1 = fjob(Pf.ow1, 64, 192, 4, 6);
    Wf.ow2 = fjob(Pf.ow2, 64, 64, 4, 2);
    Wf.ow3 = fjob(Pf.ow3, 64, 64, 4, 2);
    Wf.ow4 = fjob(Pf.ow4, 432, 64, 28, 2);
    Wf.bw1 = fjob(Pf.bw1, 64, 192, 4, 6);
    Wf.bw1KC = 6;
    Wf.bw2 = fjob(Pf.bw2, 64, 64, 4, 2);
    Wf.dw = fjobd(Pf.dw);
    frag_all_k<<<dim3(1008, 14), 256, 0, stream>>>(fj);

    pack_tr_k<<<dim3(144, 8), 256, 0, stream>>>(x, xpk);

    auto convm = [&](const unsigned* a, const unsigned* b, const unsigned* c2,
                     const ushort_t* frag, int KCfull, const float* bias,
                     const float* addsrc, unsigned* out, int act) {
        const unsigned* srcs[3] = {a, b, c2};
        const unsigned* S[3] = {nullptr, nullptr, nullptr};
        int B[3] = {0, 0, 0};
        int ns = 0;
        for (int j = 0; j < 3; ++j)
            if (srcs[j]) {
                S[ns] = srcs[j];
                B[ns] = j * 2;
                ++ns;
            }
        convm_k<<<1152, 128, 0, stream>>>(S[0], S[1], S[2], B[0], B[1], B[2],
                                          ns, frag, KCfull, bias, addsrc, out,
                                          act);
    };

    for (int dir = 0; dir < 2; ++dir) {  // 0 = backward, 1 = forward
        const DirP& P = dir ? Pf : Pb;
        const DirW& W = dir ? Wf : Wb;
        unsigned* feat = dir ? featFpk : featBpk;
        const unsigned* prev1 = nullptr;
        const unsigned* prev2 = nullptr;
        for (int i = 0; i < 8; ++i) {
            int idx = dir ? i : 7 - i;
            const unsigned* cur = xpk + (size_t)idx * FRAME;
            const float* propf = nullptr;
            if (i > 0) {
                convm(prev1, cur, prev2, W.ow1, 6, P.ob1, nullptr, hApk, 1);
                convm(hApk, nullptr, nullptr, W.ow2, 2, P.ob2, nullptr, hBpk, 1);
                convm(hBpk, nullptr, nullptr, W.ow3, 2, P.ob3, nullptr, hApk, 1);
                int ngr4 = (prev2 != nullptr) ? 4 : 2;
                dconv_fused_k<<<576, 256, 0, stream>>>(
                    prev1, prev2, hApk, W.ow4, P.ob4, W.dw, P.db, ngr4, Dbuf,
                    Dpk);
                propf = Dbuf;
            }
            unsigned* dst = feat + (size_t)idx * FRAME;
            if (dir == 0) {
                convm(cur, (i > 0) ? Dpk : nullptr, nullptr, W.bw1, W.bw1KC,
                      P.bb1, nullptr, hBpk, 1);
            } else {
                convm(cur, featBpk + (size_t)idx * FRAME,
                      (i > 0) ? Dpk : nullptr, W.bw1, W.bw1KC, P.bb1, nullptr,
                      hBpk, 1);
            }
            convm(hBpk, nullptr, nullptr, W.bw2, 2, P.bb2, propf, dst, 0);
            prev2 = prev1;
            prev1 = dst;
        }
    }

    fuse_k<<<dim3(3, 12, 64), 256, 0, stream>>>(featBpk, featFpk, x, wfus,
                                                fus_b, (float*)d_out);
}

// Round 5
// 1688.307 us; speedup vs baseline: 1.3032x; 1.0913x over previous
//
#include <hip/hip_runtime.h>
#include <cstddef>

#define HW96 9216
#define FRAME (64 * 9216)

typedef unsigned short ushort_t;
typedef __attribute__((ext_vector_type(8))) short bf16x8;
typedef __attribute__((ext_vector_type(4))) float f32x4;
typedef __attribute__((ext_vector_type(4))) unsigned u32x4;

// packed u32 = (bf16 hi bits << 16) | bf16 lo bits; value = hi + lo exactly
__device__ __forceinline__ float unpk(unsigned p) {
    return __uint_as_float(p & 0xFFFF0000u) + __uint_as_float(p << 16);
}
__device__ __forceinline__ unsigned pk(float v) {
    unsigned u = __float_as_uint(v);
    unsigned hi = u & 0xFFFF0000u;
    float rem = v - __uint_as_float(hi);
    unsigned r = __float_as_uint(rem);
    unsigned lo = (r + 0x7FFFu + ((r >> 16) & 1u)) >> 16;
    return hi | (lo & 0xFFFFu);
}
__device__ __forceinline__ void split16(float v, ushort_t& h, ushort_t& l) {
    unsigned u = __float_as_uint(v);
    h = (ushort_t)(u >> 16);
    float rem = v - __uint_as_float(u & 0xFFFF0000u);
    unsigned r = __float_as_uint(rem);
    l = (ushort_t)((r + 0x7FFFu + ((r >> 16) & 1u)) >> 16);
}

// ---------------------------------------------------------------------------
// Plain repack: OIHW -> [i][o] fp32 (fusion 1x1 only).
// ---------------------------------------------------------------------------
__global__ __launch_bounds__(256) void repack_fus_k(const float* __restrict__ w,
                                                    float* __restrict__ wp) {
    int idx = blockIdx.x * 256 + threadIdx.x;  // 128*64
    if (idx >= 128 * 64) return;
    int o = idx % 64;
    int i = idx / 64;
    wp[idx] = w[o * 128 + i];
}

// ---------------------------------------------------------------------------
// MFMA A-fragment prepack (16x16x32) with bf16 hi/lo split.
// mode 0 (3x3 conv): layout [hl][t][cc][ot][lane][j]; K = cin chunks of 32.
// mode 1 (dconv):    layout [hl][cc][ot][lane][j]; K = g*72 + tap*8 + c.
// A[m=lane&15][k=(lane>>4)*8+j].
// ---------------------------------------------------------------------------
struct FragJob { const float* src; ushort_t* dst; int O, I, OT, KC, mode; };
struct FragJobs { FragJob j[14]; };

__global__ __launch_bounds__(256) void frag_all_k(FragJobs jobs) {
    const FragJob& J = jobs.j[blockIdx.y];
    int idx = blockIdx.x * 256 + threadIdx.x;
    int total = (J.mode ? 1 : 9) * J.KC * J.OT * 512;
    if (idx >= total) return;
    int jj = idx & 7;
    int lane = (idx >> 3) & 63;
    int rem = idx >> 9;
    int ot = rem % J.OT;
    rem /= J.OT;
    int cc = rem % J.KC;
    int t = rem / J.KC;
    int o = ot * 16 + (lane & 15);
    float wv = 0.f;
    if (J.mode == 0) {
        int ci = cc * 32 + (lane >> 4) * 8 + jj;
        if (o < J.O && ci < J.I) wv = J.src[(o * J.I + ci) * 9 + t];
    } else {
        int K = cc * 32 + (lane >> 4) * 8 + jj;
        int g = K / 72, r2 = K % 72;
        int tap = r2 >> 3, c = r2 & 7;
        int ci = g * 8 + c;
        if (o < J.O && ci < J.I) wv = J.src[(o * J.I + ci) * 9 + tap];
    }
    ushort_t h, l;
    split16(wv, h, l);
    J.dst[idx] = h;
    J.dst[total + idx] = l;
}

// ---------------------------------------------------------------------------
// Transposing pack: planar fp32 frames -> interleaved [px][64ch] packed u32.
// Block handles one 64-px x 64-ch tile via padded LDS. grid (144, T).
// ---------------------------------------------------------------------------
__global__ __launch_bounds__(256) void pack_tr_k(const float* __restrict__ src,
                                                 unsigned* __restrict__ dst) {
    const int t = blockIdx.y;
    const int px0 = blockIdx.x * 64;
    __shared__ unsigned tile[64 * 65];
    const float* s = src + (size_t)t * FRAME;
    unsigned* d = dst + (size_t)t * FRAME;
#pragma unroll
    for (int it = 0; it < 16; ++it) {
        int e = it * 256 + threadIdx.x;
        int p = e & 63, ch = e >> 6;
        tile[ch * 65 + p] = pk(s[(size_t)ch * HW96 + px0 + p]);
    }
    __syncthreads();
#pragma unroll
    for (int it = 0; it < 16; ++it) {
        int e = it * 256 + threadIdx.x;
        int ch = e & 63, p = e >> 6;
        d[(size_t)(px0 + p) * 64 + ch] = tile[ch * 65 + p];
    }
}

// ---------------------------------------------------------------------------
// MFMA implicit-GEMM 3x3 conv, 16x16x32 bf16.
// TERMS=3: AhBh + AlBh + AhBl (fp32-grade, feature path: bw1/bw2).
// TERMS=2: AhBh + AhBl (weight-lo dropped; offset/mask path: ow1..ow3) —
//          halves the global weight-fragment stream, -1/3 MFMA.
// 128 thr = 2 waves; block = 32 couts (half) x 16 px; grid 1152.
// Depth-5 rolling pipeline, consume-before-fill ring discipline.
// ---------------------------------------------------------------------------
template <int TERMS>
__global__ __launch_bounds__(128, 3) void convm_k(
    const unsigned* __restrict__ s0, const unsigned* __restrict__ s1,
    const unsigned* __restrict__ s2, int b0, int b1, int b2, int nsrc,
    const ushort_t* __restrict__ wfrag, int KCfull,
    const float* __restrict__ bias, const float* __restrict__ addsrc,
    unsigned* __restrict__ outpk, int act) {
    const int tid = threadIdx.x;
    const int lane = tid & 63;
    const int w = tid >> 6;              // 0..1
    const int h = blockIdx.x & 1;       // cout half
    const int bseg = blockIdx.x >> 1;   // px segment
    const int ot = h * 2 + w;           // global out-tile 0..3
    const int xb = (bseg % 6) * 16;
    const int y = bseg / 6;
    const int n = lane & 15;
    const int quad = lane >> 4;

    __shared__ __align__(16) ushort_t ldsH[3 * 18 * 72];
    __shared__ __align__(16) ushort_t ldsL[3 * 18 * 72];

    // staging job decode (loop-invariant): 432 jobs = 54 (r,c) x 8 octets
    int jst[4], jok[4], joff[4], jbase[4];
#pragma unroll
    for (int i = 0; i < 4; ++i) {
        int e = tid + i * 128;
        int rc = e >> 3, cg = e & 7;
        int r = rc / 18, col = rc - r * 18;
        int gy = y - 1 + r, gx = xb - 1 + col;
        jst[i] = (e < 432);
        jok[i] = jst[i] && ((unsigned)gy < 96u) && ((unsigned)gx < 96u);
        joff[i] = (gy * 96 + gx) * 64 + cg * 8;
        jbase[i] = rc * 72 + cg * 8;
    }

    f32x4 acc0, acc1;
#pragma unroll
    for (int r = 0; r < 4; ++r) { acc0[r] = 0.f; acc1[r] = 0.f; }

    const size_t hlOff = (size_t)9 * KCfull * 4 * 512;

    for (int j = 0; j < nsrc; ++j) {
        const unsigned* sv = (j == 0) ? s0 : (j == 1 ? s1 : s2);
        const int base = (j == 0) ? b0 : (j == 1 ? b1 : b2);
        __syncthreads();
#pragma unroll
        for (int i = 0; i < 4; ++i) {
            if (jst[i]) {
                u32x4 a, b;
                if (jok[i]) {
                    a = *(const u32x4*)(sv + joff[i]);
                    b = *(const u32x4*)(sv + joff[i] + 4);
                } else {
#pragma unroll
                    for (int q = 0; q < 4; ++q) { a[q] = 0; b[q] = 0; }
                }
                u32x4 H, L;
#pragma unroll
                for (int q = 0; q < 2; ++q) {
                    H[q] = (a[2 * q] >> 16) | (a[2 * q + 1] & 0xFFFF0000u);
                    L[q] = (a[2 * q] & 0xFFFFu) | (a[2 * q + 1] << 16);
                    H[2 + q] = (b[2 * q] >> 16) | (b[2 * q + 1] & 0xFFFF0000u);
                    L[2 + q] = (b[2 * q] & 0xFFFFu) | (b[2 * q + 1] << 16);
                }
                *(u32x4*)(ldsH + jbase[i]) = H;
                *(u32x4*)(ldsL + jbase[i]) = L;
            }
        }
        __syncthreads();
        // depth-5 rolling pipeline over 18 steps (t = s>>1, cc2 = s&1)
        bf16x8 pAh[5], pAl[5], pBh[5], pBl[5];
#pragma unroll
        for (int s = 0; s < 23; ++s) {
            if (s >= 5) {  // consume BEFORE refilling the slot
                const int u = s - 5;
                const bf16x8 Ah = pAh[u % 5];
                const bf16x8 Bh = pBh[u % 5], Bl = pBl[u % 5];
                if (u & 1) {
                    acc1 = __builtin_amdgcn_mfma_f32_16x16x32_bf16(Ah, Bh, acc1, 0, 0, 0);
                    if (TERMS == 3)
                        acc1 = __builtin_amdgcn_mfma_f32_16x16x32_bf16(pAl[u % 5], Bh, acc1, 0, 0, 0);
                    acc1 = __builtin_amdgcn_mfma_f32_16x16x32_bf16(Ah, Bl, acc1, 0, 0, 0);
                } else {
                    acc0 = __builtin_amdgcn_mfma_f32_16x16x32_bf16(Ah, Bh, acc0, 0, 0, 0);
                    if (TERMS == 3)
                        acc0 = __builtin_amdgcn_mfma_f32_16x16x32_bf16(pAl[u % 5], Bh, acc0, 0, 0, 0);
                    acc0 = __builtin_amdgcn_mfma_f32_16x16x32_bf16(Ah, Bl, acc0, 0, 0, 0);
                }
            }
            if (s < 18) {
                const int t = s >> 1, cc2 = s & 1;
                const int ky = t / 3, kx = t % 3;
                const int ccor = base + cc2;
                const ushort_t* ab =
                    wfrag + (((size_t)(t * KCfull + ccor) * 4 + ot) * 64 + lane) * 8;
                pAh[s % 5] = *(const bf16x8*)ab;
                if (TERMS == 3) pAl[s % 5] = *(const bf16x8*)(ab + hlOff);
                const int lb = (ky * 18 + n + kx) * 72 + cc2 * 32 + quad * 8;
                pBh[s % 5] = *(const bf16x8*)(ldsH + lb);
                pBl[s % 5] = *(const bf16x8*)(ldsL + lb);
            }
        }
    }

    const int px = y * 96 + xb + n;
#pragma unroll
    for (int r = 0; r < 4; ++r) {
        int cout = ot * 16 + quad * 4 + r;
        float v = acc0[r] + acc1[r] + bias[cout];
        if (act) v = (v >= 0.f) ? v : 0.1f * v;
        if (addsrc) v += addsrc[(size_t)cout * HW96 + px];
        outpk[(size_t)px * 64 + cout] = pk(v);
    }
}

// ---------------------------------------------------------------------------
// Fused ow4 (64->432 conv) + modulated deformable conv v2.
// 256 thr = 4 waves. Phase 2 (ow4 -> offsets/masks only) now 2-term:
// AhBh + AhBl, weight-lo dropped — halves the w4 L2 stream, -1/3 MFMA.
// Phase 3 (feature path) stays 3-term. Depth-5/4 pipelines, consume-first.
// ---------------------------------------------------------------------------
__global__ __launch_bounds__(256, 3) void dconv_fused_k(
    const unsigned* __restrict__ sA, const unsigned* __restrict__ sB,
    const unsigned* __restrict__ hA, const ushort_t* __restrict__ w4,
    const float* __restrict__ ob4, const ushort_t* __restrict__ dwf,
    const float* __restrict__ dbias, int ngr4, float* __restrict__ outf,
    unsigned* __restrict__ outpk) {
    const int tid = threadIdx.x;
    const int lane = tid & 63;
    const int w = tid >> 6;
    const int xb = (blockIdx.x % 6) * 16;
    const int y = blockIdx.x / 6;
    const int n = lane & 15;
    const int quad = lane >> 4;

    __shared__ __align__(16) char smem[18944 + 448 * 17 * 4];
    ushort_t* ldsAH = (ushort_t*)smem;        // 3888 ushorts
    ushort_t* ldsAL = ldsAH + 3888;
    ushort_t* colsH = (ushort_t*)smem;        // 16*296 ushorts (union)
    ushort_t* colsL = colsH + 4736;
    float* rawS = (float*)(smem + 18944);     // [448][17] fp32

    // ---- phase 1: stage hA window (interleaved source) ----
#pragma unroll
    for (int i = 0; i < 2; ++i) {
        int e = tid + i * 256;
        if (e < 432) {
            int rc = e >> 3, cg = e & 7;
            int r = rc / 18, col = rc - r * 18;
            int gy = y - 1 + r, gx = xb - 1 + col;
            bool ok = ((unsigned)gy < 96u) && ((unsigned)gx < 96u);
            u32x4 a, b;
            if (ok) {
                int off = (gy * 96 + gx) * 64 + cg * 8;
                a = *(const u32x4*)(hA + off);
                b = *(const u32x4*)(hA + off + 4);
            } else {
#pragma unroll
                for (int q = 0; q < 4; ++q) { a[q] = 0; b[q] = 0; }
            }
            u32x4 H, L;
#pragma unroll
            for (int q = 0; q < 2; ++q) {
                H[q] = (a[2 * q] >> 16) | (a[2 * q + 1] & 0xFFFF0000u);
                L[q] = (a[2 * q] & 0xFFFFu) | (a[2 * q + 1] << 16);
                H[2 + q] = (b[2 * q] >> 16) | (b[2 * q + 1] & 0xFFFF0000u);
                L[2 + q] = (b[2 * q] & 0xFFFFu) | (b[2 * q + 1] << 16);
            }
            *(u32x4*)(ldsAH + rc * 72 + cg * 8) = H;
            *(u32x4*)(ldsAL + rc * 72 + cg * 8) = L;
        }
    }
    __syncthreads();

    // ---- phase 2: raw = ow4(hA), 7 out-tiles per wave, 2-term, depth-5 ----
#pragma unroll 1
    for (int j = 0; j < 7; ++j) {
        const int ot = j * 4 + w;
        f32x4 a0, a1;
#pragma unroll
        for (int r = 0; r < 4; ++r) { a0[r] = 0.f; a1[r] = 0.f; }
        bf16x8 pAh[5], pBh[5], pBl[5];
#pragma unroll
        for (int s = 0; s < 23; ++s) {
            if (s >= 5) {  // consume BEFORE refilling the slot
                const int u = s - 5;
                const bf16x8 Ah = pAh[u % 5];
                const bf16x8 Bh = pBh[u % 5], Bl = pBl[u % 5];
                if (u & 1) {
                    a1 = __builtin_amdgcn_mfma_f32_16x16x32_bf16(Ah, Bh, a1, 0, 0, 0);
                    a1 = __builtin_amdgcn_mfma_f32_16x16x32_bf16(Ah, Bl, a1, 0, 0, 0);
                } else {
                    a0 = __builtin_amdgcn_mfma_f32_16x16x32_bf16(Ah, Bh, a0, 0, 0, 0);
                    a0 = __builtin_amdgcn_mfma_f32_16x16x32_bf16(Ah, Bl, a0, 0, 0, 0);
                }
            }
            if (s < 18) {
                const int t = s >> 1, cc2 = s & 1;
                const int ky = t / 3, kx = t % 3;
                const ushort_t* ab =
                    w4 + (((size_t)s * 28 + ot) * 64 + lane) * 8;
                pAh[s % 5] = *(const bf16x8*)ab;
                const int lb = (ky * 18 + n + kx) * 72 + cc2 * 32 + quad * 8;
                pBh[s % 5] = *(const bf16x8*)(ldsAH + lb);
                pBl[s % 5] = *(const bf16x8*)(ldsAL + lb);
            }
        }
#pragma unroll
        for (int r = 0; r < 4; ++r) {
            int cout = ot * 16 + quad * 4 + r;
            float v = a0[r] + a1[r] + (cout < 432 ? ob4[cout] : 0.f);
            rawS[cout * 17 + n] = v;
        }
    }

    // ---- phase 3: gather + dconv MFMA (3-term, depth-4 pipeline) ----
    f32x4 acc0, acc1;
#pragma unroll
    for (int r = 0; r < 4; ++r) { acc0[r] = 0.f; acc1[r] = 0.f; }
    const size_t hlD = (size_t)36 * 4 * 512;

    for (int gc = 0; gc < ngr4; ++gc) {
        __syncthreads();  // rawS ready / cols reuse safe
#pragma unroll
        for (int i = 0; i < 3; ++i) {
            int e = tid + i * 256;
            if (e < 576) {
                int p = e & 15;
                int r = e >> 4;  // 0..35
                int gl = r / 9, k = r - gl * 9;
                int g = gc * 4 + gl;
                float ry = rawS[(g * 18 + k * 2 + 0) * 17 + p];
                float rx = rawS[(g * 18 + k * 2 + 1) * 17 + p];
                float rm = rawS[(288 + g * 9 + k) * 17 + p];
                float oy = 5.f * (1.f - 2.f / (1.f + __expf(2.f * ry)));
                float ox = 5.f * (1.f - 2.f / (1.f + __expf(2.f * rx)));
                float m = 1.f / (1.f + __expf(-rm));
                float sy = oy + (float)(y - 1 + k / 3);
                float sx = ox + (float)(xb + p - 1 + k % 3);
                float fy0 = floorf(sy), fx0 = floorf(sx);
                float fy = sy - fy0, fx = sx - fx0;
                int y0 = (int)fy0, x0 = (int)fx0;
                int y1 = y0 + 1, x1 = x0 + 1;
                bool vy0 = (unsigned)y0 < 96u, vy1 = (unsigned)y1 < 96u;
                bool vx0 = (unsigned)x0 < 96u, vx1 = (unsigned)x1 < 96u;
                int cy0 = min(max(y0, 0), 95), cy1 = min(max(y1, 0), 95);
                int cx0 = min(max(x0, 0), 95), cx1 = min(max(x1, 0), 95);
                float w00 = (1.f - fy) * (1.f - fx) * ((vy0 && vx0) ? 1.f : 0.f);
                float w01 = (1.f - fy) * fx * ((vy0 && vx1) ? 1.f : 0.f);
                float w10 = fy * (1.f - fx) * ((vy1 && vx0) ? 1.f : 0.f);
                float w11 = fy * fx * ((vy1 && vx1) ? 1.f : 0.f);
                const unsigned* src = (g < 8) ? sA : sB;
                int cb = (g & 7) * 8;
                int kbase = p * 296 + gl * 72 + k * 8;
                ushort_t hh[8], ll[8];
                if (src) {
                    int b00 = (cy0 * 96 + cx0) * 64 + cb;
                    int b01 = (cy0 * 96 + cx1) * 64 + cb;
                    int b10 = (cy1 * 96 + cx0) * 64 + cb;
                    int b11 = (cy1 * 96 + cx1) * 64 + cb;
                    u32x4 c00a = *(const u32x4*)(src + b00);
                    u32x4 c00b = *(const u32x4*)(src + b00 + 4);
                    u32x4 c01a = *(const u32x4*)(src + b01);
                    u32x4 c01b = *(const u32x4*)(src + b01 + 4);
                    u32x4 c10a = *(const u32x4*)(src + b10);
                    u32x4 c10b = *(const u32x4*)(src + b10 + 4);
                    u32x4 c11a = *(const u32x4*)(src + b11);
                    u32x4 c11b = *(const u32x4*)(src + b11 + 4);
#pragma unroll
                    for (int c = 0; c < 4; ++c) {
                        float v = w00 * unpk(c00a[c]) + w01 * unpk(c01a[c]) +
                                  w10 * unpk(c10a[c]) + w11 * unpk(c11a[c]);
                        split16(v * m, hh[c], ll[c]);
                        float v2 = w00 * unpk(c00b[c]) + w01 * unpk(c01b[c]) +
                                   w10 * unpk(c10b[c]) + w11 * unpk(c11b[c]);
                        split16(v2 * m, hh[4 + c], ll[4 + c]);
                    }
                } else {
#pragma unroll
                    for (int c = 0; c < 8; ++c) { hh[c] = 0; ll[c] = 0; }
                }
                u32x4 H, L;
#pragma unroll
                for (int q = 0; q < 4; ++q) {
                    H[q] = (unsigned)hh[2 * q] | ((unsigned)hh[2 * q + 1] << 16);
                    L[q] = (unsigned)ll[2 * q] | ((unsigned)ll[2 * q + 1] << 16);
                }
                *(u32x4*)(colsH + kbase) = H;
                *(u32x4*)(colsL + kbase) = L;
            }
        }
        __syncthreads();
        bf16x8 qAh[4], qAl[4], qBh[4], qBl[4];
#pragma unroll
        for (int s = 0; s < 13; ++s) {
            if (s >= 4) {  // consume BEFORE refilling the slot
                const int u = s - 4;
                const bf16x8 Ah = qAh[u % 4], Al = qAl[u % 4];
                const bf16x8 Bh = qBh[u % 4], Bl = qBl[u % 4];
                if (u & 1) {
                    acc1 = __builtin_amdgcn_mfma_f32_16x16x32_bf16(Ah, Bh, acc1, 0, 0, 0);
                    acc1 = __builtin_amdgcn_mfma_f32_16x16x32_bf16(Al, Bh, acc1, 0, 0, 0);
                    acc1 = __builtin_amdgcn_mfma_f32_16x16x32_bf16(Ah, Bl, acc1, 0, 0, 0);
                } else {
                    acc0 = __builtin_amdgcn_mfma_f32_16x16x32_bf16(Ah, Bh, acc0, 0, 0, 0);
                    acc0 = __builtin_amdgcn_mfma_f32_16x16x32_bf16(Al, Bh, acc0, 0, 0, 0);
                    acc0 = __builtin_amdgcn_mfma_f32_16x16x32_bf16(Ah, Bl, acc0, 0, 0, 0);
                }
            }
            if (s < 9) {
                const int cc = gc * 9 + s;
                const ushort_t* ab = dwf + (((size_t)cc * 4 + w) * 64 + lane) * 8;
                qAh[s % 4] = *(const bf16x8*)ab;
                qAl[s % 4] = *(const bf16x8*)(ab + hlD);
                const int lb = n * 296 + s * 32 + quad * 8;
                qBh[s % 4] = *(const bf16x8*)(colsH + lb);
                qBl[s % 4] = *(const bf16x8*)(colsL + lb);
            }
        }
    }

    const int pidx = y * 96 + xb + n;
#pragma unroll
    for (int r = 0; r < 4; ++r) {
        int cout = w * 16 + quad * 4 + r;
        float v = acc0[r] + acc1[r] + dbias[cout];
        outf[(size_t)cout * HW96 + pidx] = v;
        outpk[(size_t)pidx * 64 + cout] = pk(v);
    }
}

// ---------------------------------------------------------------------------
// Fusion: 1x1 conv over [featB[t], featF[t]] (interleaved) + bias + x.
// ---------------------------------------------------------------------------
__global__ __launch_bounds__(256) void fuse_k(
    const unsigned* __restrict__ featB, const unsigned* __restrict__ featF,
    const float* __restrict__ x, const float* __restrict__ wp,
    const float* __restrict__ bias, float* __restrict__ out) {
    const int tx = threadIdx.x & 31;
    const int ty = threadIdx.x >> 5;
    const int px = blockIdx.x * 32 + tx;
    const int py = blockIdx.y * 8 + ty;
    const int t = blockIdx.z >> 3;
    const int obase = (blockIdx.z & 7) * 8;
    const int pidx = py * 96 + px;
    const unsigned* fB = featB + (size_t)t * FRAME + (size_t)pidx * 64;
    const unsigned* fF = featF + (size_t)t * FRAME + (size_t)pidx * 64;

    float acc[8];
#pragma unroll
    for (int o = 0; o < 8; ++o) acc[o] = 0.f;

#pragma unroll 4
    for (int i0 = 0; i0 < 64; i0 += 4) {
        u32x4 pv = *(const u32x4*)(fB + i0);
#pragma unroll
        for (int q = 0; q < 4; ++q) {
            float v = unpk(pv[q]);
            const float* wr = wp + (i0 + q) * 64 + obase;
#pragma unroll
            for (int o = 0; o < 8; ++o) acc[o] = fmaf(wr[o], v, acc[o]);
        }
    }
#pragma unroll 4
    for (int i0 = 0; i0 < 64; i0 += 4) {
        u32x4 pv = *(const u32x4*)(fF + i0);
#pragma unroll
        for (int q = 0; q < 4; ++q) {
            float v = unpk(pv[q]);
            const float* wr = wp + (64 + i0 + q) * 64 + obase;
#pragma unroll
            for (int o = 0; o < 8; ++o) acc[o] = fmaf(wr[o], v, acc[o]);
        }
    }
    const float* xt = x + (size_t)t * FRAME;
#pragma unroll
    for (int o = 0; o < 8; ++o)
        out[(size_t)t * FRAME + (size_t)(obase + o) * HW96 + pidx] =
            acc[o] + bias[obase + o] + xt[(size_t)(obase + o) * HW96 + pidx];
}

// ---------------------------------------------------------------------------
extern "C" void kernel_launch(void* const* d_in, const int* in_sizes, int n_in,
                              void* d_out, int out_size, void* d_ws,
                              size_t ws_size, hipStream_t stream) {
    const float* x = (const float*)d_in[0];
    auto gp = [&](int i) { return (const float*)d_in[i]; };

    struct DirP {
        const float *dw, *db, *ow1, *ob1, *ow2, *ob2, *ow3, *ob3, *ow4, *ob4,
            *bw1, *bb1, *bw2, *bb2;
    };
    DirP Pb{gp(1), gp(2), gp(3), gp(4), gp(5), gp(6), gp(7),
            gp(8), gp(9), gp(10), gp(11), gp(12), gp(13), gp(14)};
    DirP Pf{gp(15), gp(16), gp(17), gp(18), gp(19), gp(20), gp(21),
            gp(22), gp(23), gp(24), gp(25), gp(26), gp(27), gp(28)};
    const float* fus_w = gp(29);
    const float* fus_b = gp(30);

    // ---- workspace carve-up (4-byte units); all feature bufs interleaved ----
    unsigned* featBpk = (unsigned*)d_ws;
    unsigned* featFpk = featBpk + (size_t)8 * FRAME;
    unsigned* xpk = featFpk + (size_t)8 * FRAME;
    float* Dbuf = (float*)(xpk + (size_t)8 * FRAME);  // planar fp32
    unsigned* Dpk = (unsigned*)(Dbuf + FRAME);        // interleaved packed
    unsigned* hApk = Dpk + FRAME;
    unsigned* hBpk = hApk + FRAME;
    float* wfus = (float*)(hBpk + FRAME);
    ushort_t* fragp = (ushort_t*)(wfus + 128 * 64);

    auto falloc = [&](size_t nelem) {
        ushort_t* p = fragp;
        fragp += nelem;
        return p;
    };

    // ---- weight prep ----
    repack_fus_k<<<32, 256, 0, stream>>>(fus_w, wfus);

    struct DirW { ushort_t *ow1, *ow2, *ow3, *ow4, *bw1, *bw2, *dw; int bw1KC; };
    FragJobs fj;
    int nf = 0;
    auto fjob = [&](const float* src, int O, int I, int OT, int KC) {
        ushort_t* dst = falloc((size_t)2 * 9 * KC * OT * 512);
        fj.j[nf++] = FragJob{src, dst, O, I, OT, KC, 0};
        return dst;
    };
    auto fjobd = [&](const float* src) {
        ushort_t* dst = falloc((size_t)2 * 36 * 4 * 512);
        fj.j[nf++] = FragJob{src, dst, 64, 128, 4, 36, 1};
        return dst;
    };
    DirW Wb, Wf;
    Wb.ow1 = fjob(Pb.ow1, 64, 192, 4, 6);
    Wb.ow2 = fjob(Pb.ow2, 64, 64, 4, 2);
    Wb.ow3 = fjob(Pb.ow3, 64, 64, 4, 2);
    Wb.ow4 = fjob(Pb.ow4, 432, 64, 28, 2);
    Wb.bw1 = fjob(Pb.bw1, 64, 128, 4, 4);
    Wb.bw1KC = 4;
    Wb.bw2 = fjob(Pb.bw2, 64, 64, 4, 2);
    Wb.dw = fjobd(Pb.dw);
    Wf.ow1 = fjob(Pf.ow1, 64, 192, 4, 6);
    Wf.ow2 = fjob(Pf.ow2, 64, 64, 4, 2);
    Wf.ow3 = fjob(Pf.ow3, 64, 64, 4, 2);
    Wf.ow4 = fjob(Pf.ow4, 432, 64, 28, 2);
    Wf.bw1 = fjob(Pf.bw1, 64, 192, 4, 6);
    Wf.bw1KC = 6;
    Wf.bw2 = fjob(Pf.bw2, 64, 64, 4, 2);
    Wf.dw = fjobd(Pf.dw);
    frag_all_k<<<dim3(1008, 14), 256, 0, stream>>>(fj);

    pack_tr_k<<<dim3(144, 8), 256, 0, stream>>>(x, xpk);

    auto convm = [&](const unsigned* a, const unsigned* b, const unsigned* c2,
                     const ushort_t* frag, int KCfull, const float* bias,
                     const float* addsrc, unsigned* out, int act, int terms) {
        const unsigned* srcs[3] = {a, b, c2};
        const unsigned* S[3] = {nullptr, nullptr, nullptr};
        int B[3] = {0, 0, 0};
        int ns = 0;
        for (int j = 0; j < 3; ++j)
            if (srcs[j]) {
                S[ns] = srcs[j];
                B[ns] = j * 2;
                ++ns;
            }
        if (terms == 2)
            convm_k<2><<<1152, 128, 0, stream>>>(S[0], S[1], S[2], B[0], B[1],
                                                 B[2], ns, frag, KCfull, bias,
                                                 addsrc, out, act);
        else
            convm_k<3><<<1152, 128, 0, stream>>>(S[0], S[1], S[2], B[0], B[1],
                                                 B[2], ns, frag, KCfull, bias,
                                                 addsrc, out, act);
    };

    for (int dir = 0; dir < 2; ++dir) {  // 0 = backward, 1 = forward
        const DirP& P = dir ? Pf : Pb;
        const DirW& W = dir ? Wf : Wb;
        unsigned* feat = dir ? featFpk : featBpk;
        const unsigned* prev1 = nullptr;
        const unsigned* prev2 = nullptr;
        for (int i = 0; i < 8; ++i) {
            int idx = dir ? i : 7 - i;
            const unsigned* cur = xpk + (size_t)idx * FRAME;
            const float* propf = nullptr;
            if (i > 0) {
                // offset/mask path: 2-term (weight-lo dropped)
                convm(prev1, cur, prev2, W.ow1, 6, P.ob1, nullptr, hApk, 1, 2);
                convm(hApk, nullptr, nullptr, W.ow2, 2, P.ob2, nullptr, hBpk, 1, 2);
                convm(hBpk, nullptr, nullptr, W.ow3, 2, P.ob3, nullptr, hApk, 1, 2);
                int ngr4 = (prev2 != nullptr) ? 4 : 2;
                dconv_fused_k<<<576, 256, 0, stream>>>(
                    prev1, prev2, hApk, W.ow4, P.ob4, W.dw, P.db, ngr4, Dbuf,
                    Dpk);
                propf = Dbuf;
            }
            unsigned* dst = feat + (size_t)idx * FRAME;
            // feature path: keep 3-term
            if (dir == 0) {
                convm(cur, (i > 0) ? Dpk : nullptr, nullptr, W.bw1, W.bw1KC,
                      P.bb1, nullptr, hBpk, 1, 3);
            } else {
                convm(cur, featBpk + (size_t)idx * FRAME,
                      (i > 0) ? Dpk : nullptr, W.bw1, W.bw1KC, P.bb1, nullptr,
                      hBpk, 1, 3);
            }
            convm(hBpk, nullptr, nullptr, W.bw2, 2, P.bb2, propf, dst, 0, 3);
            prev2 = prev1;
            prev1 = dst;
        }
    }

    fuse_k<<<dim3(3, 12, 64), 256, 0, stream>>>(featBpk, featFpk, x, wfus,
                                                fus_b, (float*)d_out);
}